// Round 5
// baseline (342.512 us; speedup 1.0000x reference)
//
#include <hip/hip_runtime.h>
#include <hip/hip_bf16.h>

#define N_NODES 50000
#define N_EDGES 600000

typedef short bf16x8 __attribute__((ext_vector_type(8)));
typedef float f32x4 __attribute__((ext_vector_type(4)));

__device__ __forceinline__ float leaky(float e) { return fmaxf(e, 0.2f * e); }
__device__ __forceinline__ unsigned short f2b(float f) {
  __hip_bfloat16 h = __float2bfloat16(f);
  return *reinterpret_cast<unsigned short*>(&h);
}
__device__ __forceinline__ float blo(unsigned int u) { return __uint_as_float(u << 16); }
__device__ __forceinline__ float bhi(unsigned int u) { return __uint_as_float(u & 0xffff0000u); }

// ------- edge convert (detect int64 vs int32) + degree count + weight prep -------
// Only dst is read here (deg count); k_fill re-reads the edge list directly.
// WtG1 stacked [c(128)][k(256)] (k<128 head0, k>=128 head1) for the K=256 GEMM.
// was/wad = W_gat @ a_{src,dst} (logits are linear in h -> fused into epilogues).
__global__ void k_convert(const int* __restrict__ e, int* __restrict__ deg,
                          int* __restrict__ flag,
                          const float* __restrict__ W1, const float* __restrict__ WG1,
                          const float* __restrict__ W2, const float* __restrict__ WG2,
                          unsigned short* __restrict__ Wt1, unsigned short* __restrict__ WtG1,
                          unsigned short* __restrict__ Wt2, unsigned short* __restrict__ WtG2,
                          const float* b1, const float* g1, const float* be1, const float* m1,
                          const float* v1, const float* b2, const float* g2, const float* be2,
                          const float* m2, const float* v2, float* sc1, float* sh1,
                          float* sc2, float* sh2,
                          const float* as1, const float* ad1, const float* as2,
                          const float* ad2, float* was1, float* wad1, float* was2,
                          float* wad2) {
  __shared__ int sflag;
  int tid = threadIdx.x;
  if (tid < 64) {  // wave 0: sample odd int32 words; all-zero => int64 input
    int idx = 1 + 2 * tid * 4096;
    int v = e[idx];
    unsigned long long nz = __ballot(v != 0);
    if (tid == 0) sflag = (nz == 0ULL) ? 1 : 0;
  }
  __syncthreads();
  int f = sflag;
  int i = blockIdx.x * 256 + tid;
  if (i == 0) flag[0] = f;
  if (i < N_EDGES) {
    int d = f ? e[2 * (N_EDGES + i)] : e[N_EDGES + i];
    atomicAdd(&deg[d], 1);
  }
  // fused prep (independent outputs, same index space)
  if (i < 16384) {
    int k = i >> 7, c = i & 127;
    Wt1[c * 128 + k] = f2b(W1[i]);
  } else if (i < 49152) {
    int l = i - 16384;                 // l = k*256 + c8
    int k = l >> 8, c8 = l & 255;
    int head = c8 >> 7, cc = c8 & 127;
    WtG1[cc * 256 + head * 128 + k] = f2b(WG1[l]);  // stacked [c][256]
  } else if (i < 65536) {
    int l = i - 49152;
    int k = l >> 7, c = l & 127;
    Wt2[c * 128 + k] = f2b(W2[l]);
  } else if (i < 81920) {
    int l = i - 65536;
    int k = l >> 7, c = l & 127;
    WtG2[c * 128 + k] = f2b(WG2[l]);
  } else if (i < 82048) {
    int c = i - 81920;
    float s = g1[c] * rsqrtf(v1[c] + 1e-5f);
    sc1[c] = s;
    sh1[c] = (b1[c] - m1[c]) * s + be1[c];
  } else if (i < 82176) {
    int c = i - 82048;
    float s = g2[c] * rsqrtf(v2[c] + 1e-5f);
    sc2[c] = s;
    sh2[c] = (b2[c] - m2[c]) * s + be2[c];
  } else if (i < 82688) {
    // was/wad[k][h] = sum_c WG[k][h*HL+c] * a[h*HL+c]   (layout [128][2], h inner)
    int j = i - 82176;
    int k = j & 127;
    int vec = j >> 7;  // 0=was1 1=wad1 2=was2 3=wad2
    const float* Wr = (vec < 2) ? (WG1 + k * 256) : (WG2 + k * 128);
    const float* av = (vec == 0) ? as1 : (vec == 1) ? ad1 : (vec == 2) ? as2 : ad2;
    float* op = (vec == 0) ? was1 : (vec == 1) ? wad1 : (vec == 2) ? was2 : wad2;
    int hl = (vec < 2) ? 128 : 64;
    float s0 = 0.f, s1 = 0.f;
    for (int c = 0; c < hl; c += 4) {
      float4 wv = *(const float4*)(Wr + c);
      float4 a4 = *(const float4*)(av + c);
      s0 += wv.x * a4.x + wv.y * a4.y + wv.z * a4.z + wv.w * a4.w;
    }
    for (int c = 0; c < hl; c += 4) {
      float4 wv = *(const float4*)(Wr + hl + c);
      float4 a4 = *(const float4*)(av + hl + c);
      s1 += wv.x * a4.x + wv.y * a4.y + wv.z * a4.z + wv.w * a4.w;
    }
    op[2 * k] = s0;
    op[2 * k + 1] = s1;
  }
}

// ---- CSR offsets: block-local scan + atomic block base.
// roff is NOT globally monotone — consumers use end = roff[i] + deg[i].
__global__ void k_offsets(const int* __restrict__ deg, int* __restrict__ gbase,
                          int* __restrict__ roff, int* __restrict__ cursor,
                          float* __restrict__ dinv) {
  __shared__ int s[256];
  __shared__ int base;
  int t = threadIdx.x;
  int i = blockIdx.x * 256 + t;
  int v = (i < N_NODES) ? deg[i] : 0;
  s[t] = v;
  __syncthreads();
  for (int o = 1; o < 256; o <<= 1) {
    int x = (t >= o) ? s[t - o] : 0;
    __syncthreads();
    s[t] += x;
    __syncthreads();
  }
  if (t == 255) base = atomicAdd(gbase, s[255]);
  __syncthreads();
  int off = base + s[t] - v;
  if (i < N_NODES) {
    roff[i] = off;
    cursor[i] = off;
    dinv[i] = rsqrtf((float)v + 1.f);
  }
}
// fill CSR slots straight from the input edge list: aen = {src, bits(dinv[src])}
__global__ void k_fill(const int* __restrict__ e, const int* __restrict__ flag,
                       int* __restrict__ cursor, int2* __restrict__ aen,
                       const float* __restrict__ dinv) {
  int f = flag[0];
  int i = blockIdx.x * 256 + threadIdx.x;
  if (i < N_EDGES) {
    int s, d;
    if (f) { s = e[2 * i]; d = e[2 * (N_EDGES + i)]; }
    else   { s = e[i];     d = e[N_EDGES + i]; }
    int pos = atomicAdd(&cursor[d], 1);
    aen[pos] = make_int2(s, __float_as_int(dinv[s]));
  }
}

// ---------------- MFMA GEMM: Hb[n,128] = bf16( X[n,128] @ W[128,128] ) --------
// W in registers, A staged in LDS, acc held across all 4 row-tiles, LDS repack
// epilogue -> uint4 stores (was 32 scalar 2B stores/lane).
__global__ __launch_bounds__(256, 4) void gemm_mfma(const float* __restrict__ X,
                                                    const unsigned short* __restrict__ Wt,
                                                    unsigned short* __restrict__ Hb) {
  __shared__ __align__(16) short smem[64 * 136];
  int tid = threadIdx.x;
  int row0 = blockIdx.x * 64;
  for (int i = tid; i < 2048; i += 256) {
    int r = i >> 5;
    int k4 = (i & 31) * 4;
    int row = row0 + r;
    float4 v = make_float4(0.f, 0.f, 0.f, 0.f);
    if (row < N_NODES) v = *(const float4*)(X + (size_t)row * 128 + k4);
    uint2 p;
    p.x = (unsigned int)f2b(v.x) | ((unsigned int)f2b(v.y) << 16);
    p.y = (unsigned int)f2b(v.z) | ((unsigned int)f2b(v.w) << 16);
    *(uint2*)&smem[r * 136 + k4] = p;
  }
  int wave = tid >> 6, lane = tid & 63;
  int m = lane & 15, quad = lane >> 4;
  int c0 = wave * 32;
  bf16x8 b[2][4];
#pragma unroll
  for (int ct = 0; ct < 2; ++ct) {
    const unsigned short* wp = Wt + (size_t)(c0 + ct * 16 + m) * 128 + quad * 8;
#pragma unroll
    for (int kk = 0; kk < 4; ++kk) b[ct][kk] = *(const bf16x8*)(wp + kk * 32);
  }
  __syncthreads();
  f32x4 acc[4][2];
#pragma unroll
  for (int rt = 0; rt < 4; ++rt)
#pragma unroll
    for (int ct = 0; ct < 2; ++ct) acc[rt][ct] = (f32x4){0.f, 0.f, 0.f, 0.f};
#pragma unroll
  for (int rt = 0; rt < 4; ++rt) {
    bf16x8 a[4];
#pragma unroll
    for (int kk = 0; kk < 4; ++kk)
      a[kk] = *(const bf16x8*)&smem[(rt * 16 + m) * 136 + kk * 32 + quad * 8];
#pragma unroll
    for (int ct = 0; ct < 2; ++ct)
#pragma unroll
      for (int kk = 0; kk < 4; ++kk)
        acc[rt][ct] = __builtin_amdgcn_mfma_f32_16x16x32_bf16(a[kk], b[ct][kk], acc[rt][ct], 0, 0, 0);
  }
  __syncthreads();  // all waves done reading A
#pragma unroll
  for (int rt = 0; rt < 4; ++rt)
#pragma unroll
    for (int ct = 0; ct < 2; ++ct)
#pragma unroll
      for (int reg = 0; reg < 4; ++reg)
        smem[(rt * 16 + quad * 4 + reg) * 128 + c0 + ct * 16 + m] = (short)f2b(acc[rt][ct][reg]);
  __syncthreads();
  for (int i = tid; i < 1024; i += 256) {
    int row = row0 + (i >> 4);
    if (row < N_NODES)
      *(uint4*)((char*)Hb + (size_t)row0 * 256 + (size_t)i * 16) =
          *(uint4*)((char*)smem + (size_t)i * 16);
  }
}

// -------- K=256 MFMA GEMM + bias+relu: G[n,128] = relu(Q[n,256]@Wt + b) ----
// Q bf16; K staged in two 128-halves through one LDS tile; repack epilogue.
__global__ __launch_bounds__(256, 4) void gemm_k256(const unsigned short* __restrict__ Q,
                                                    const unsigned short* __restrict__ Wt,
                                                    const float* __restrict__ bias,
                                                    unsigned short* __restrict__ G) {
  __shared__ __align__(16) short smem[64 * 136];
  int tid = threadIdx.x;
  int row0 = blockIdx.x * 64;
  int wave = tid >> 6, lane = tid & 63;
  int m = lane & 15, quad = lane >> 4;
  int c0 = wave * 32;
  f32x4 acc[4][2];
#pragma unroll
  for (int rt = 0; rt < 4; ++rt)
#pragma unroll
    for (int ct = 0; ct < 2; ++ct) acc[rt][ct] = (f32x4){0.f, 0.f, 0.f, 0.f};
#pragma unroll
  for (int half = 0; half < 2; ++half) {
    if (half) __syncthreads();
    for (int i = tid; i < 2048; i += 256) {
      int r = i >> 5;
      int k4 = (i & 31) * 4;
      int row = row0 + r;
      uint2 p = make_uint2(0u, 0u);
      if (row < N_NODES) p = *(const uint2*)(Q + (size_t)row * 256 + half * 128 + k4);
      *(uint2*)&smem[r * 136 + k4] = p;
    }
    bf16x8 b[2][4];
#pragma unroll
    for (int ct = 0; ct < 2; ++ct) {
      const unsigned short* wp =
          Wt + (size_t)(c0 + ct * 16 + m) * 256 + half * 128 + quad * 8;
#pragma unroll
      for (int kk = 0; kk < 4; ++kk) b[ct][kk] = *(const bf16x8*)(wp + kk * 32);
    }
    __syncthreads();
#pragma unroll
    for (int rt = 0; rt < 4; ++rt) {
      bf16x8 a[4];
#pragma unroll
      for (int kk = 0; kk < 4; ++kk)
        a[kk] = *(const bf16x8*)&smem[(rt * 16 + m) * 136 + kk * 32 + quad * 8];
#pragma unroll
      for (int ct = 0; ct < 2; ++ct)
#pragma unroll
        for (int kk = 0; kk < 4; ++kk)
          acc[rt][ct] =
              __builtin_amdgcn_mfma_f32_16x16x32_bf16(a[kk], b[ct][kk], acc[rt][ct], 0, 0, 0);
    }
  }
  __syncthreads();
  float bv[2];
#pragma unroll
  for (int ct = 0; ct < 2; ++ct) bv[ct] = bias[c0 + ct * 16 + m];
#pragma unroll
  for (int rt = 0; rt < 4; ++rt)
#pragma unroll
    for (int ct = 0; ct < 2; ++ct)
#pragma unroll
      for (int reg = 0; reg < 4; ++reg)
        smem[(rt * 16 + quad * 4 + reg) * 128 + c0 + ct * 16 + m] =
            (short)f2b(fmaxf(acc[rt][ct][reg] + bv[ct], 0.f));
  __syncthreads();
  for (int i = tid; i < 1024; i += 256) {
    int row = row0 + (i >> 4);
    if (row < N_NODES)
      *(uint4*)((char*)G + (size_t)row0 * 256 + (size_t)i * 16) =
          *(uint4*)((char*)smem + (size_t)i * 16);
  }
}

// -------- Fused GCN2+GAT2-projection double GEMM:
// P2 = relu(BN(AG @ W2))  (stage1, LDS-resident)
// Q2 = P2 @ WG2           (stage2)
// als/ald = P2 @ was/wad  (epilogue from the LDS tile)
// Deletes the Hb2/Pb round-trips of the old gemm->pull->gemm chain.
__global__ __launch_bounds__(256, 4) void gemm_gcn2_gat2(
    const unsigned short* __restrict__ AG, const unsigned short* __restrict__ Wt2,
    const float* __restrict__ sc, const float* __restrict__ sh,
    const unsigned short* __restrict__ WtG2,
    const float* __restrict__ was, const float* __restrict__ wad,
    float* __restrict__ als, float* __restrict__ ald,
    unsigned short* __restrict__ Q2) {
  __shared__ __align__(16) short smA[64 * 136];
  __shared__ __align__(16) short smB[64 * 136];
  int tid = threadIdx.x;
  int row0 = blockIdx.x * 64;
  // stage AG tile (bf16, raw copy)
  for (int i = tid; i < 1024; i += 256) {
    int r = i >> 4;
    int k8 = (i & 15) * 8;
    int row = row0 + r;
    uint4 p = make_uint4(0u, 0u, 0u, 0u);
    if (row < N_NODES) p = *(const uint4*)(AG + (size_t)row * 128 + k8);
    *(uint4*)&smA[r * 136 + k8] = p;
  }
  int wave = tid >> 6, lane = tid & 63;
  int m = lane & 15, quad = lane >> 4;
  int c0 = wave * 32;
  bf16x8 b1[2][4];
#pragma unroll
  for (int ct = 0; ct < 2; ++ct) {
    const unsigned short* wp = Wt2 + (size_t)(c0 + ct * 16 + m) * 128 + quad * 8;
#pragma unroll
    for (int kk = 0; kk < 4; ++kk) b1[ct][kk] = *(const bf16x8*)(wp + kk * 32);
  }
  __syncthreads();
  f32x4 acc[4][2];
#pragma unroll
  for (int rt = 0; rt < 4; ++rt)
#pragma unroll
    for (int ct = 0; ct < 2; ++ct) acc[rt][ct] = (f32x4){0.f, 0.f, 0.f, 0.f};
#pragma unroll
  for (int rt = 0; rt < 4; ++rt) {
    bf16x8 a[4];
#pragma unroll
    for (int kk = 0; kk < 4; ++kk)
      a[kk] = *(const bf16x8*)&smA[(rt * 16 + m) * 136 + kk * 32 + quad * 8];
#pragma unroll
    for (int ct = 0; ct < 2; ++ct)
#pragma unroll
      for (int kk = 0; kk < 4; ++kk)
        acc[rt][ct] = __builtin_amdgcn_mfma_f32_16x16x32_bf16(a[kk], b1[ct][kk], acc[rt][ct], 0, 0, 0);
  }
  // P2 = relu(acc*sc+sh) -> smB (each wave owns its 32-col slice; no race)
  float scv[2], shv[2];
#pragma unroll
  for (int ct = 0; ct < 2; ++ct) {
    scv[ct] = sc[c0 + ct * 16 + m];
    shv[ct] = sh[c0 + ct * 16 + m];
  }
#pragma unroll
  for (int rt = 0; rt < 4; ++rt)
#pragma unroll
    for (int ct = 0; ct < 2; ++ct)
#pragma unroll
      for (int reg = 0; reg < 4; ++reg)
        smB[(rt * 16 + quad * 4 + reg) * 136 + c0 + ct * 16 + m] =
            (short)f2b(fmaxf(fmaf(acc[rt][ct][reg], scv[ct], shv[ct]), 0.f));
  __syncthreads();  // P2 complete before cross-wave reads
  // stage2: Q2 = P2 @ WG2
  bf16x8 b2[2][4];
#pragma unroll
  for (int ct = 0; ct < 2; ++ct) {
    const unsigned short* wp = WtG2 + (size_t)(c0 + ct * 16 + m) * 128 + quad * 8;
#pragma unroll
    for (int kk = 0; kk < 4; ++kk) b2[ct][kk] = *(const bf16x8*)(wp + kk * 32);
  }
  f32x4 acc2[4][2];
#pragma unroll
  for (int rt = 0; rt < 4; ++rt)
#pragma unroll
    for (int ct = 0; ct < 2; ++ct) acc2[rt][ct] = (f32x4){0.f, 0.f, 0.f, 0.f};
#pragma unroll
  for (int rt = 0; rt < 4; ++rt) {
    bf16x8 a[4];
#pragma unroll
    for (int kk = 0; kk < 4; ++kk)
      a[kk] = *(const bf16x8*)&smB[(rt * 16 + m) * 136 + kk * 32 + quad * 8];
#pragma unroll
    for (int ct = 0; ct < 2; ++ct)
#pragma unroll
      for (int kk = 0; kk < 4; ++kk)
        acc2[rt][ct] = __builtin_amdgcn_mfma_f32_16x16x32_bf16(a[kk], b2[ct][kk], acc2[rt][ct], 0, 0, 0);
  }
  // GAT2 logits from the LDS P2 tile: wave handles rows wave*16..+15, 4 lanes/row
  {
    int rloc = wave * 16 + (lane >> 2);
    int k0 = (lane & 3) * 32;
    float s0 = 0.f, s1 = 0.f, d0 = 0.f, d1 = 0.f;
#pragma unroll
    for (int c = 0; c < 32; c += 2) {
      unsigned u = *(const unsigned*)&smB[rloc * 136 + k0 + c];
      float x0 = blo(u), x1 = bhi(u);
      float4 ws4 = *(const float4*)(was + 2 * (k0 + c));
      float4 wd4 = *(const float4*)(wad + 2 * (k0 + c));
      s0 = fmaf(x0, ws4.x, s0); s1 = fmaf(x0, ws4.y, s1);
      s0 = fmaf(x1, ws4.z, s0); s1 = fmaf(x1, ws4.w, s1);
      d0 = fmaf(x0, wd4.x, d0); d1 = fmaf(x0, wd4.y, d1);
      d0 = fmaf(x1, wd4.z, d0); d1 = fmaf(x1, wd4.w, d1);
    }
#pragma unroll
    for (int mask = 1; mask <= 2; mask <<= 1) {
      s0 += __shfl_xor(s0, mask, 64);
      s1 += __shfl_xor(s1, mask, 64);
      d0 += __shfl_xor(d0, mask, 64);
      d1 += __shfl_xor(d1, mask, 64);
    }
    int row = row0 + rloc;
    if ((lane & 3) == 0 && row < N_NODES) {
      *(float2*)(als + 2 * row) = make_float2(s0, s1);
      *(float2*)(ald + 2 * row) = make_float2(d0, d1);
    }
  }
  // repack Q2 into smA (dead) -> uint4 stores
#pragma unroll
  for (int rt = 0; rt < 4; ++rt)
#pragma unroll
    for (int ct = 0; ct < 2; ++ct)
#pragma unroll
      for (int reg = 0; reg < 4; ++reg)
        smA[(rt * 16 + quad * 4 + reg) * 128 + c0 + ct * 16 + m] =
            (short)f2b(acc2[rt][ct][reg]);
  __syncthreads();
  for (int i = tid; i < 1024; i += 256) {
    int row = row0 + (i >> 4);
    if (row < N_NODES)
      *(uint4*)((char*)Q2 + (size_t)row0 * 256 + (size_t)i * 16) =
          *(uint4*)((char*)smA + (size_t)i * 16);
  }
}

// ---- GCN aggregation: 4 nodes/wave; lane-distributed edge meta, 8 gathers in
// ---- flight, prefetch, branchless full batches + one predicated partial.
// ---- MODE 0: epilogue fuses BN+relu + GAT logit dots.  MODE 1: raw agg out.
template <int MODE>
__global__ __launch_bounds__(256) void gcn_pull(const unsigned short* __restrict__ Hb,
                                                const int2* __restrict__ aen,
                                                const int* __restrict__ roff,
                                                const int* __restrict__ deg,
                                                const float* __restrict__ dinv,
                                                const float* __restrict__ sc,
                                                const float* __restrict__ sh,
                                                const float* __restrict__ was,
                                                const float* __restrict__ wad,
                                                float* __restrict__ als,
                                                float* __restrict__ ald,
                                                unsigned short* __restrict__ out) {
  int wv = (blockIdx.x * 256 + threadIdx.x) >> 6;
  int lane = threadIdx.x & 63;
  int q4 = lane >> 4, l16 = lane & 15;
  int qb = lane & 48, l7 = lane & 7;
  int i = 4 * wv + q4;
  if (i >= N_NODES) return;
  int off = roff[i], end = off + deg[i];
  float di = dinv[i];
  uint4 u = *(const uint4*)((const char*)Hb + (unsigned)i * 256u + l16 * 16u);
  float a0 = blo(u.x) * di, a1 = bhi(u.x) * di;
  float a2 = blo(u.y) * di, a3 = bhi(u.y) * di;
  float a4 = blo(u.z) * di, a5 = bhi(u.z) * di;
  float a6 = blo(u.w) * di, a7 = bhi(u.w) * di;  // self-loop
  int j = off;
  int nfull = (end - off) >> 3;
  int2 ae = make_int2(i, 0);
  if (l7 < end - j) ae = aen[j + l7];
  for (int t = 0; t < nfull; ++t) {
    int ss[8];
#pragma unroll
    for (int k = 0; k < 8; ++k) ss[k] = __shfl(ae.x, qb + k, 64);
    float ww[8];
#pragma unroll
    for (int k = 0; k < 8; ++k) ww[k] = __shfl(__int_as_float(ae.y), qb + k, 64);
    uint4 vv[8];
#pragma unroll
    for (int k = 0; k < 8; ++k)
      vv[k] = *(const uint4*)((const char*)Hb + (unsigned)ss[k] * 256u + l16 * 16u);
    j += 8;
    if (l7 < end - j) ae = aen[j + l7];  // prefetch next batch
#pragma unroll
    for (int k = 0; k < 8; ++k) {
      a0 = fmaf(blo(vv[k].x), ww[k], a0); a1 = fmaf(bhi(vv[k].x), ww[k], a1);
      a2 = fmaf(blo(vv[k].y), ww[k], a2); a3 = fmaf(bhi(vv[k].y), ww[k], a3);
      a4 = fmaf(blo(vv[k].z), ww[k], a4); a5 = fmaf(bhi(vv[k].z), ww[k], a5);
      a6 = fmaf(blo(vv[k].w), ww[k], a6); a7 = fmaf(bhi(vv[k].w), ww[k], a7);
    }
  }
  int rem = end - j;
  if (rem) {
    int ss[8];
#pragma unroll
    for (int k = 0; k < 8; ++k) ss[k] = __shfl(ae.x, qb + k, 64);
    float ww[8];
#pragma unroll
    for (int k = 0; k < 8; ++k) ww[k] = __shfl(__int_as_float(ae.y), qb + k, 64);
    uint4 vv[8];
#pragma unroll
    for (int k = 0; k < 8; ++k)
      if (k < rem)
        vv[k] = *(const uint4*)((const char*)Hb + (unsigned)ss[k] * 256u + l16 * 16u);
#pragma unroll
    for (int k = 0; k < 8; ++k)
      if (k < rem) {
        a0 = fmaf(blo(vv[k].x), ww[k], a0); a1 = fmaf(bhi(vv[k].x), ww[k], a1);
        a2 = fmaf(blo(vv[k].y), ww[k], a2); a3 = fmaf(bhi(vv[k].y), ww[k], a3);
        a4 = fmaf(blo(vv[k].z), ww[k], a4); a5 = fmaf(bhi(vv[k].z), ww[k], a5);
        a6 = fmaf(blo(vv[k].w), ww[k], a6); a7 = fmaf(bhi(vv[k].w), ww[k], a7);
      }
  }
  if constexpr (MODE == 1) {
    // raw symmetric-normalized aggregate, bf16
    uint4 pw;
    pw.x = (unsigned int)f2b(a0 * di) | ((unsigned int)f2b(a1 * di) << 16);
    pw.y = (unsigned int)f2b(a2 * di) | ((unsigned int)f2b(a3 * di) << 16);
    pw.z = (unsigned int)f2b(a4 * di) | ((unsigned int)f2b(a5 * di) << 16);
    pw.w = (unsigned int)f2b(a6 * di) | ((unsigned int)f2b(a7 * di) << 16);
    *(uint4*)(out + (size_t)i * 128 + l16 * 8) = pw;
  } else {
    // epilogue: BN + relu (fp32), GAT logit dots, bf16 pack
    int c0 = l16 * 8;
    float4 sca = *(const float4*)(sc + c0), scb = *(const float4*)(sc + c0 + 4);
    float4 sha = *(const float4*)(sh + c0), shb = *(const float4*)(sh + c0 + 4);
    float t0 = fmaxf(fmaf(a0 * di, sca.x, sha.x), 0.f);
    float t1 = fmaxf(fmaf(a1 * di, sca.y, sha.y), 0.f);
    float t2 = fmaxf(fmaf(a2 * di, sca.z, sha.z), 0.f);
    float t3 = fmaxf(fmaf(a3 * di, sca.w, sha.w), 0.f);
    float t4 = fmaxf(fmaf(a4 * di, scb.x, shb.x), 0.f);
    float t5 = fmaxf(fmaf(a5 * di, scb.y, shb.y), 0.f);
    float t6 = fmaxf(fmaf(a6 * di, scb.z, shb.z), 0.f);
    float t7 = fmaxf(fmaf(a7 * di, scb.w, shb.w), 0.f);
    float4 w0 = *(const float4*)(was + 2 * c0);
    float4 w1 = *(const float4*)(was + 2 * c0 + 4);
    float4 w2 = *(const float4*)(was + 2 * c0 + 8);
    float4 w3 = *(const float4*)(was + 2 * c0 + 12);
    float sl0 = t0 * w0.x + t1 * w0.z + t2 * w1.x + t3 * w1.z +
                t4 * w2.x + t5 * w2.z + t6 * w3.x + t7 * w3.z;
    float sl1 = t0 * w0.y + t1 * w0.w + t2 * w1.y + t3 * w1.w +
                t4 * w2.y + t5 * w2.w + t6 * w3.y + t7 * w3.w;
    w0 = *(const float4*)(wad + 2 * c0);
    w1 = *(const float4*)(wad + 2 * c0 + 4);
    w2 = *(const float4*)(wad + 2 * c0 + 8);
    w3 = *(const float4*)(wad + 2 * c0 + 12);
    float dl0 = t0 * w0.x + t1 * w0.z + t2 * w1.x + t3 * w1.z +
                t4 * w2.x + t5 * w2.z + t6 * w3.x + t7 * w3.z;
    float dl1 = t0 * w0.y + t1 * w0.w + t2 * w1.y + t3 * w1.w +
                t4 * w2.y + t5 * w2.w + t6 * w3.y + t7 * w3.w;
#pragma unroll
    for (int mask = 1; mask <= 8; mask <<= 1) {
      sl0 += __shfl_xor(sl0, mask, 64);
      sl1 += __shfl_xor(sl1, mask, 64);
      dl0 += __shfl_xor(dl0, mask, 64);
      dl1 += __shfl_xor(dl1, mask, 64);
    }
    if (l16 == 0) {
      *(float2*)(als + 2 * i) = make_float2(sl0, sl1);
      *(float2*)(ald + 2 * i) = make_float2(dl0, dl1);
    }
    uint4 pw;
    pw.x = (unsigned int)f2b(t0) | ((unsigned int)f2b(t1) << 16);
    pw.y = (unsigned int)f2b(t2) | ((unsigned int)f2b(t3) << 16);
    pw.z = (unsigned int)f2b(t4) | ((unsigned int)f2b(t5) << 16);
    pw.w = (unsigned int)f2b(t6) | ((unsigned int)f2b(t7) << 16);
    *(uint4*)(out + (size_t)i * 128 + l16 * 8) = pw;
  }
}

// -------- GAT-1 aggregation over P (pre-GEMM, 256B rows): one row read per
// -------- edge serves BOTH heads. Q[i] = [r0*agg0 | r1*agg1], r_h=0.5/den_h.
__global__ __launch_bounds__(256) void gat1_pull(const unsigned short* __restrict__ P,
                                                 const int2* __restrict__ aen,
                                                 const int* __restrict__ roff,
                                                 const int* __restrict__ deg,
                                                 const float* __restrict__ als,
                                                 const float* __restrict__ ald,
                                                 unsigned short* __restrict__ Q) {
  int wv = (blockIdx.x * 256 + threadIdx.x) >> 6;
  int lane = threadIdx.x & 63;
  int q4 = lane >> 4, l16 = lane & 15;
  int qb = lane & 48, l7 = lane & 7;
  int i = 4 * wv + q4;
  if (i >= N_NODES) return;
  int off = roff[i], end = off + deg[i];
  float2 dif = *(const float2*)(ald + 2 * i);
  float p0 = 0.f, p1 = 0.f;
  float g0 = 0.f, g1 = 0.f, g2 = 0.f, g3 = 0.f,
        g4 = 0.f, g5 = 0.f, g6 = 0.f, g7 = 0.f;  // head0
  float h0 = 0.f, h1 = 0.f, h2 = 0.f, h3 = 0.f,
        h4 = 0.f, h5 = 0.f, h6 = 0.f, h7 = 0.f;  // head1
  int j = off;
  int nfull = (end - off) >> 3;
  int2 ae = make_int2(i, 0);
  float2 av = make_float2(-1e30f, -1e30f);
  if (l7 < end - j) {
    ae = aen[j + l7];
    av = *(const float2*)(als + 2 * ae.x);
  }
  for (int t = 0; t < nfull; ++t) {
    int ss[8];
#pragma unroll
    for (int k = 0; k < 8; ++k) ss[k] = __shfl(ae.x, qb + k, 64);
    uint4 vv[8];
#pragma unroll
    for (int k = 0; k < 8; ++k)
      vv[k] = *(const uint4*)((const char*)P + (unsigned)ss[k] * 256u + l16 * 16u);
    float q0 = __expf(leaky(av.x + dif.x));
    float q1 = __expf(leaky(av.y + dif.y));
    j += 8;
    if (l7 < end - j) {
      ae = aen[j + l7];
      av = *(const float2*)(als + 2 * ae.x);
    }
#pragma unroll
    for (int k = 0; k < 8; ++k) {
      float b0 = __shfl(q0, qb + k, 64);
      float b1 = __shfl(q1, qb + k, 64);
      p0 += b0; p1 += b1;
      float c0 = blo(vv[k].x), c1 = bhi(vv[k].x);
      float c2 = blo(vv[k].y), c3 = bhi(vv[k].y);
      float c4 = blo(vv[k].z), c5 = bhi(vv[k].z);
      float c6 = blo(vv[k].w), c7 = bhi(vv[k].w);
      g0 = fmaf(b0, c0, g0); h0 = fmaf(b1, c0, h0);
      g1 = fmaf(b0, c1, g1); h1 = fmaf(b1, c1, h1);
      g2 = fmaf(b0, c2, g2); h2 = fmaf(b1, c2, h2);
      g3 = fmaf(b0, c3, g3); h3 = fmaf(b1, c3, h3);
      g4 = fmaf(b0, c4, g4); h4 = fmaf(b1, c4, h4);
      g5 = fmaf(b0, c5, g5); h5 = fmaf(b1, c5, h5);
      g6 = fmaf(b0, c6, g6); h6 = fmaf(b1, c6, h6);
      g7 = fmaf(b0, c7, g7); h7 = fmaf(b1, c7, h7);
    }
  }
  int rem = end - j;
  if (rem) {
    int ss[8];
#pragma unroll
    for (int k = 0; k < 8; ++k) ss[k] = __shfl(ae.x, qb + k, 64);
    uint4 vv[8];
#pragma unroll
    for (int k = 0; k < 8; ++k)
      if (k < rem)
        vv[k] = *(const uint4*)((const char*)P + (unsigned)ss[k] * 256u + l16 * 16u);
    float q0 = __expf(leaky(av.x + dif.x));
    float q1 = __expf(leaky(av.y + dif.y));
#pragma unroll
    for (int k = 0; k < 8; ++k)
      if (k < rem) {
        float b0 = __shfl(q0, qb + k, 64);
        float b1 = __shfl(q1, qb + k, 64);
        p0 += b0; p1 += b1;
        float c0 = blo(vv[k].x), c1 = bhi(vv[k].x);
        float c2 = blo(vv[k].y), c3 = bhi(vv[k].y);
        float c4 = blo(vv[k].z), c5 = bhi(vv[k].z);
        float c6 = blo(vv[k].w), c7 = bhi(vv[k].w);
        g0 = fmaf(b0, c0, g0); h0 = fmaf(b1, c0, h0);
        g1 = fmaf(b0, c1, g1); h1 = fmaf(b1, c1, h1);
        g2 = fmaf(b0, c2, g2); h2 = fmaf(b1, c2, h2);
        g3 = fmaf(b0, c3, g3); h3 = fmaf(b1, c3, h3);
        g4 = fmaf(b0, c4, g4); h4 = fmaf(b1, c4, h4);
        g5 = fmaf(b0, c5, g5); h5 = fmaf(b1, c5, h5);
        g6 = fmaf(b0, c6, g6); h6 = fmaf(b1, c6, h6);
        g7 = fmaf(b0, c7, g7); h7 = fmaf(b1, c7, h7);
      }
  }
  float2 ai = *(const float2*)(als + 2 * i);
  float es0 = __expf(leaky(ai.x + dif.x));
  float es1 = __expf(leaky(ai.y + dif.y));
  float r0 = 0.5f / (p0 + es0);
  float r1 = 0.5f / (p1 + es1);
  uint4 u = *(const uint4*)((const char*)P + (unsigned)i * 256u + l16 * 16u);
  float c0 = blo(u.x), c1 = bhi(u.x), c2 = blo(u.y), c3 = bhi(u.y);
  float c4 = blo(u.z), c5 = bhi(u.z), c6 = blo(u.w), c7 = bhi(u.w);
  g0 = (g0 + es0 * c0) * r0; g1 = (g1 + es0 * c1) * r0;
  g2 = (g2 + es0 * c2) * r0; g3 = (g3 + es0 * c3) * r0;
  g4 = (g4 + es0 * c4) * r0; g5 = (g5 + es0 * c5) * r0;
  g6 = (g6 + es0 * c6) * r0; g7 = (g7 + es0 * c7) * r0;
  h0 = (h0 + es1 * c0) * r1; h1 = (h1 + es1 * c1) * r1;
  h2 = (h2 + es1 * c2) * r1; h3 = (h3 + es1 * c3) * r1;
  h4 = (h4 + es1 * c4) * r1; h5 = (h5 + es1 * c5) * r1;
  h6 = (h6 + es1 * c6) * r1; h7 = (h7 + es1 * c7) * r1;
  uint4 pw;
  pw.x = (unsigned int)f2b(g0) | ((unsigned int)f2b(g1) << 16);
  pw.y = (unsigned int)f2b(g2) | ((unsigned int)f2b(g3) << 16);
  pw.z = (unsigned int)f2b(g4) | ((unsigned int)f2b(g5) << 16);
  pw.w = (unsigned int)f2b(g6) | ((unsigned int)f2b(g7) << 16);
  *(uint4*)(Q + (size_t)i * 256 + l16 * 8) = pw;
  pw.x = (unsigned int)f2b(h0) | ((unsigned int)f2b(h1) << 16);
  pw.y = (unsigned int)f2b(h2) | ((unsigned int)f2b(h3) << 16);
  pw.z = (unsigned int)f2b(h4) | ((unsigned int)f2b(h5) << 16);
  pw.w = (unsigned int)f2b(h6) | ((unsigned int)f2b(h7) << 16);
  *(uint4*)(Q + (size_t)i * 256 + 128 + l16 * 8) = pw;
}

// ---- GAT HD=64 + fused log_softmax: 4 nodes/wave (16 lanes x 16B = 256B row).
__global__ __launch_bounds__(256) void gat_pull64_lsm(const unsigned short* __restrict__ Hb,
                                                      const int2* __restrict__ aen,
                                                      const int* __restrict__ roff,
                                                      const int* __restrict__ deg,
                                                      const float* __restrict__ als,
                                                      const float* __restrict__ ald,
                                                      const float* __restrict__ bias,
                                                      float* __restrict__ out) {
  int wv = (blockIdx.x * 256 + threadIdx.x) >> 6;
  int lane = threadIdx.x & 63;
  int q4 = lane >> 4, l16 = lane & 15;
  int qb = lane & 48, l7 = lane & 7;
  int hh = l16 >> 3, p8 = l16 & 7;
  int i = 4 * wv + q4;
  if (i >= N_NODES) return;
  int off = roff[i], end = off + deg[i];
  unsigned cb2 = (unsigned)(hh * 64 + 8 * p8) * 2u;
  float2 dd = *(const float2*)(ald + 2 * i);
  float p = 0.f;
  float acc0 = 0.f, acc1 = 0.f, acc2 = 0.f, acc3 = 0.f;
  float acc4 = 0.f, acc5 = 0.f, acc6 = 0.f, acc7 = 0.f;
  int j = off;
  int nfull = (end - off) >> 3;
  int2 ae = make_int2(i, 0);
  float2 av = make_float2(-1e30f, -1e30f);
  if (l7 < end - j) {
    ae = aen[j + l7];
    av = *(const float2*)(als + 2 * ae.x);
  }
  for (int t = 0; t < nfull; ++t) {
    int ss[8];
#pragma unroll
    for (int k = 0; k < 8; ++k) ss[k] = __shfl(ae.x, qb + k, 64);
    uint4 vv[8];
#pragma unroll
    for (int k = 0; k < 8; ++k)
      vv[k] = *(const uint4*)((const char*)Hb + (unsigned)ss[k] * 256u + cb2);
    float q0 = __expf(leaky(av.x + dd.x));
    float q1 = __expf(leaky(av.y + dd.y));
    j += 8;
    if (l7 < end - j) {
      ae = aen[j + l7];
      av = *(const float2*)(als + 2 * ae.x);
    }
#pragma unroll
    for (int k = 0; k < 8; ++k) {
      float b0 = __shfl(q0, qb + k, 64);
      float b1 = __shfl(q1, qb + k, 64);
      float q = hh ? b1 : b0;
      p += q;
      acc0 = fmaf(q, blo(vv[k].x), acc0); acc1 = fmaf(q, bhi(vv[k].x), acc1);
      acc2 = fmaf(q, blo(vv[k].y), acc2); acc3 = fmaf(q, bhi(vv[k].y), acc3);
      acc4 = fmaf(q, blo(vv[k].z), acc4); acc5 = fmaf(q, bhi(vv[k].z), acc5);
      acc6 = fmaf(q, blo(vv[k].w), acc6); acc7 = fmaf(q, bhi(vv[k].w), acc7);
    }
  }
  int rem = end - j;
  if (rem) {
    int ss[8];
#pragma unroll
    for (int k = 0; k < 8; ++k) ss[k] = __shfl(ae.x, qb + k, 64);
    uint4 vv[8];
#pragma unroll
    for (int k = 0; k < 8; ++k)
      if (k < rem)
        vv[k] = *(const uint4*)((const char*)Hb + (unsigned)ss[k] * 256u + cb2);
    float q0 = __expf(leaky(av.x + dd.x));
    float q1 = __expf(leaky(av.y + dd.y));
#pragma unroll
    for (int k = 0; k < 8; ++k)
      if (k < rem) {
        float b0 = __shfl(q0, qb + k, 64);
        float b1 = __shfl(q1, qb + k, 64);
        float q = hh ? b1 : b0;
        p += q;
        acc0 = fmaf(q, blo(vv[k].x), acc0); acc1 = fmaf(q, bhi(vv[k].x), acc1);
        acc2 = fmaf(q, blo(vv[k].y), acc2); acc3 = fmaf(q, bhi(vv[k].y), acc3);
        acc4 = fmaf(q, blo(vv[k].z), acc4); acc5 = fmaf(q, bhi(vv[k].z), acc5);
        acc6 = fmaf(q, blo(vv[k].w), acc6); acc7 = fmaf(q, bhi(vv[k].w), acc7);
      }
  }
  float2 ai = *(const float2*)(als + 2 * i);
  float axs = hh ? ai.y : ai.x;
  float dh = hh ? dd.y : dd.x;
  float es = __expf(leaky(axs + dh));
  float rsel = 0.5f / (p + es);
  uint4 u = *(const uint4*)((const char*)Hb + (unsigned)i * 256u + cb2);
  acc0 = (acc0 + es * blo(u.x)) * rsel; acc1 = (acc1 + es * bhi(u.x)) * rsel;
  acc2 = (acc2 + es * blo(u.y)) * rsel; acc3 = (acc3 + es * bhi(u.y)) * rsel;
  acc4 = (acc4 + es * blo(u.z)) * rsel; acc5 = (acc5 + es * bhi(u.z)) * rsel;
  acc6 = (acc6 + es * blo(u.w)) * rsel; acc7 = (acc7 + es * bhi(u.w)) * rsel;
  acc0 += __shfl_xor(acc0, 8, 64); acc1 += __shfl_xor(acc1, 8, 64);
  acc2 += __shfl_xor(acc2, 8, 64); acc3 += __shfl_xor(acc3, 8, 64);
  acc4 += __shfl_xor(acc4, 8, 64); acc5 += __shfl_xor(acc5, 8, 64);
  acc6 += __shfl_xor(acc6, 8, 64); acc7 += __shfl_xor(acc7, 8, 64);
  float4 b0 = *(const float4*)(bias + 8 * p8);
  float4 b1 = *(const float4*)(bias + 8 * p8 + 4);
  float v0 = acc0 + b0.x, v1 = acc1 + b0.y, v2 = acc2 + b0.z, v3 = acc3 + b0.w;
  float v4 = acc4 + b1.x, v5 = acc5 + b1.y, v6 = acc6 + b1.z, v7 = acc7 + b1.w;
  float mv = fmaxf(fmaxf(fmaxf(v0, v1), fmaxf(v2, v3)),
                   fmaxf(fmaxf(v4, v5), fmaxf(v6, v7)));
#pragma unroll
  for (int mm = 4; mm > 0; mm >>= 1) mv = fmaxf(mv, __shfl_xor(mv, mm, 64));
  float sv = __expf(v0 - mv) + __expf(v1 - mv) + __expf(v2 - mv) + __expf(v3 - mv) +
             __expf(v4 - mv) + __expf(v5 - mv) + __expf(v6 - mv) + __expf(v7 - mv);
#pragma unroll
  for (int mm = 4; mm > 0; mm >>= 1) sv += __shfl_xor(sv, mm, 64);
  float ls = mv + __logf(sv);
  if (hh == 0) {
    *(float4*)(out + (size_t)i * 64 + 8 * p8) =
        make_float4(v0 - ls, v1 - ls, v2 - ls, v3 - ls);
    *(float4*)(out + (size_t)i * 64 + 8 * p8 + 4) =
        make_float4(v4 - ls, v5 - ls, v6 - ls, v7 - ls);
  }
}

extern "C" void kernel_launch(void* const* d_in, const int* in_sizes, int n_in, void* d_out,
                              int out_size, void* d_ws, size_t ws_size, hipStream_t stream) {
  const float* x      = (const float*)d_in[0];
  const int* eidx     = (const int*)d_in[1];
  const float* W_gcn1 = (const float*)d_in[2];
  const float* b_gcn1 = (const float*)d_in[3];
  const float* bn1_g  = (const float*)d_in[4];
  const float* bn1_b  = (const float*)d_in[5];
  const float* bn1_m  = (const float*)d_in[6];
  const float* bn1_v  = (const float*)d_in[7];
  const float* W_gat1 = (const float*)d_in[8];
  const float* a_src1 = (const float*)d_in[9];
  const float* a_dst1 = (const float*)d_in[10];
  const float* b_gat1 = (const float*)d_in[11];
  const float* W_gcn2 = (const float*)d_in[12];
  const float* b_gcn2 = (const float*)d_in[13];
  const float* bn2_g  = (const float*)d_in[14];
  const float* bn2_b  = (const float*)d_in[15];
  const float* bn2_m  = (const float*)d_in[16];
  const float* bn2_v  = (const float*)d_in[17];
  const float* W_gat2 = (const float*)d_in[18];
  const float* a_src2 = (const float*)d_in[19];
  const float* a_dst2 = (const float*)d_in[20];
  const float* b_gat2 = (const float*)d_in[21];

  char* ws = (char*)d_ws;
  size_t o = 0;
  auto take = [&](size_t bytes) {
    char* p = ws + o;
    o = (o + bytes + 255) & ~(size_t)255;
    return p;
  };
  int* deg     = (int*)take((size_t)(N_NODES + 64) * 4);  // +1 int (gbase)
  int* gbase   = deg + N_NODES;
  int* flagb   = (int*)take(256);
  int* roff    = (int*)take((size_t)N_NODES * 4);
  int* cursor  = (int*)take((size_t)N_NODES * 4);
  int2* aen    = (int2*)take((size_t)N_EDGES * 8);
  float* dinv  = (float*)take((size_t)N_NODES * 4);
  float* als   = (float*)take((size_t)2 * N_NODES * 4);
  float* ald   = (float*)take((size_t)2 * N_NODES * 4);
  float* sc1   = (float*)take(128 * 4);
  float* sh1   = (float*)take(128 * 4);
  float* sc2   = (float*)take(128 * 4);
  float* sh2   = (float*)take(128 * 4);
  float* was1  = (float*)take(256 * 4);
  float* wad1  = (float*)take(256 * 4);
  float* was2  = (float*)take(256 * 4);
  float* wad2  = (float*)take(256 * 4);
  unsigned short* Wt1  = (unsigned short*)take((size_t)128 * 128 * 2);
  unsigned short* WtG1 = (unsigned short*)take((size_t)128 * 256 * 2);  // stacked [c][256]
  unsigned short* Wt2  = (unsigned short*)take((size_t)128 * 128 * 2);
  unsigned short* WtG2 = (unsigned short*)take((size_t)128 * 128 * 2);
  unsigned short* Hb   = (unsigned short*)take((size_t)N_NODES * 128 * 2);
  unsigned short* Pb   = (unsigned short*)take((size_t)N_NODES * 128 * 2);
  unsigned short* Qb   = (unsigned short*)take((size_t)N_NODES * 256 * 2);
  unsigned short* Gb   = (unsigned short*)take((size_t)N_NODES * 128 * 2);
  unsigned short* AGb  = (unsigned short*)take((size_t)N_NODES * 128 * 2);
  unsigned short* Q2b  = (unsigned short*)take((size_t)N_NODES * 128 * 2);
  (void)ws_size; (void)in_sizes; (void)n_in; (void)out_size;

  int eb = (N_EDGES + 255) / 256;
  int nb = (N_NODES + 255) / 256;
  int qb = ((N_NODES + 3) / 4 + 3) / 4;    // wave per 4 nodes (pull kernels)
  int gb = (N_NODES + 63) / 64;            // MFMA-GEMM blocks

  // CSR build + prep
  hipMemsetAsync(deg, 0, (size_t)(N_NODES + 1) * 4, stream);
  k_convert<<<eb, 256, 0, stream>>>(eidx, deg, flagb, W_gcn1, W_gat1, W_gcn2, W_gat2,
                                    Wt1, WtG1, Wt2, WtG2, b_gcn1, bn1_g, bn1_b, bn1_m, bn1_v,
                                    b_gcn2, bn2_g, bn2_b, bn2_m, bn2_v, sc1, sh1, sc2, sh2,
                                    a_src1, a_dst1, a_src2, a_dst2, was1, wad1, was2, wad2);
  k_offsets<<<nb, 256, 0, stream>>>(deg, gbase, roff, cursor, dinv);
  k_fill<<<eb, 256, 0, stream>>>(eidx, flagb, cursor, aen, dinv);

  // Layer pipeline:
  //  L1 GCN : gemm(x@W1) -> gcn_pull<0> (BN+relu+logits1)
  //  L2 GAT : gat1_pull (dual-head agg of P) -> gemm_k256 (stacked W, bias, relu)
  //  L3 GCN + L4 GAT proj: gcn_pull<1> (raw agg) -> fused double GEMM (+logits2)
  //  L4 GAT : gat_pull64_lsm
  gemm_mfma<<<gb, 256, 0, stream>>>(x, Wt1, Hb);
  gcn_pull<0><<<qb, 256, 0, stream>>>(Hb, aen, roff, deg, dinv, sc1, sh1, was1, wad1,
                                      als, ald, Pb);
  gat1_pull<<<qb, 256, 0, stream>>>(Pb, aen, roff, deg, als, ald, Qb);
  gemm_k256<<<gb, 256, 0, stream>>>(Qb, WtG1, b_gat1, Gb);
  gcn_pull<1><<<qb, 256, 0, stream>>>(Gb, aen, roff, deg, dinv, nullptr, nullptr,
                                      nullptr, nullptr, nullptr, nullptr, AGb);
  gemm_gcn2_gat2<<<gb, 256, 0, stream>>>(AGb, Wt2, sc2, sh2, WtG2, was2, wad2,
                                         als, ald, Q2b);
  gat_pull64_lsm<<<qb, 256, 0, stream>>>(Q2b, aen, roff, deg, als, ald, b_gat2,
                                         (float*)d_out);
}

// Round 6
// 314.235 us; speedup vs baseline: 1.0900x; 1.0900x over previous
//
#include <hip/hip_runtime.h>
#include <hip/hip_bf16.h>

#define N_NODES 50000
#define N_EDGES 600000

typedef short bf16x8 __attribute__((ext_vector_type(8)));
typedef float f32x4 __attribute__((ext_vector_type(4)));

__device__ __forceinline__ float leaky(float e) { return fmaxf(e, 0.2f * e); }
__device__ __forceinline__ unsigned short f2b(float f) {
  __hip_bfloat16 h = __float2bfloat16(f);
  return *reinterpret_cast<unsigned short*>(&h);
}
__device__ __forceinline__ float blo(unsigned int u) { return __uint_as_float(u << 16); }
__device__ __forceinline__ float bhi(unsigned int u) { return __uint_as_float(u & 0xffff0000u); }

// ------- edge convert (detect int64 vs int32) + degree count + weight prep -------
// The deg atomic's return value IS the CSR slot: eord[i] = {src, (d<<16)|pos}
// so k_fill needs NO atomic (and never touches the int64 edge list).
// WtG1 stacked [c(128)][k(256)] (k<128 head0, k>=128 head1) for the K=256 GEMM.
// was/wad = W_gat @ a_{src,dst} (logits are linear in h -> fused into epilogues).
__global__ void k_convert(const int* __restrict__ e, int* __restrict__ deg,
                          int2* __restrict__ eord,
                          const float* __restrict__ W1, const float* __restrict__ WG1,
                          const float* __restrict__ W2, const float* __restrict__ WG2,
                          unsigned short* __restrict__ Wt1, unsigned short* __restrict__ WtG1,
                          unsigned short* __restrict__ Wt2, unsigned short* __restrict__ WtG2,
                          const float* b1, const float* g1, const float* be1, const float* m1,
                          const float* v1, const float* b2, const float* g2, const float* be2,
                          const float* m2, const float* v2, float* sc1, float* sh1,
                          float* sc2, float* sh2,
                          const float* as1, const float* ad1, const float* as2,
                          const float* ad2, float* was1, float* wad1, float* was2,
                          float* wad2) {
  __shared__ int sflag;
  int tid = threadIdx.x;
  if (tid < 64) {  // wave 0: sample odd int32 words; all-zero => int64 input
    int idx = 1 + 2 * tid * 4096;
    int v = e[idx];
    unsigned long long nz = __ballot(v != 0);
    if (tid == 0) sflag = (nz == 0ULL) ? 1 : 0;
  }
  __syncthreads();
  int f = sflag;
  int i = blockIdx.x * 256 + tid;
  if (i < N_EDGES) {
    int s, d;
    if (f) { s = e[2 * i]; d = e[2 * (N_EDGES + i)]; }
    else   { s = e[i];     d = e[N_EDGES + i]; }
    int pos = atomicAdd(&deg[d], 1);
    eord[i] = make_int2(s, (d << 16) | pos);  // d<65536, pos<=maxdeg (~40): safe
  }
  // fused prep (independent outputs, same index space)
  if (i < 16384) {
    int k = i >> 7, c = i & 127;
    Wt1[c * 128 + k] = f2b(W1[i]);
  } else if (i < 49152) {
    int l = i - 16384;                 // l = k*256 + c8
    int k = l >> 8, c8 = l & 255;
    int head = c8 >> 7, cc = c8 & 127;
    WtG1[cc * 256 + head * 128 + k] = f2b(WG1[l]);  // stacked [c][256]
  } else if (i < 65536) {
    int l = i - 49152;
    int k = l >> 7, c = l & 127;
    Wt2[c * 128 + k] = f2b(W2[l]);
  } else if (i < 81920) {
    int l = i - 65536;
    int k = l >> 7, c = l & 127;
    WtG2[c * 128 + k] = f2b(WG2[l]);
  } else if (i < 82048) {
    int c = i - 81920;
    float s = g1[c] * rsqrtf(v1[c] + 1e-5f);
    sc1[c] = s;
    sh1[c] = (b1[c] - m1[c]) * s + be1[c];
  } else if (i < 82176) {
    int c = i - 82048;
    float s = g2[c] * rsqrtf(v2[c] + 1e-5f);
    sc2[c] = s;
    sh2[c] = (b2[c] - m2[c]) * s + be2[c];
  } else if (i < 82688) {
    // was/wad[k][h] = sum_c WG[k][h*HL+c] * a[h*HL+c]   (layout [128][2], h inner)
    int j = i - 82176;
    int k = j & 127;
    int vec = j >> 7;  // 0=was1 1=wad1 2=was2 3=wad2
    const float* Wr = (vec < 2) ? (WG1 + k * 256) : (WG2 + k * 128);
    const float* av = (vec == 0) ? as1 : (vec == 1) ? ad1 : (vec == 2) ? as2 : ad2;
    float* op = (vec == 0) ? was1 : (vec == 1) ? wad1 : (vec == 2) ? was2 : wad2;
    int hl = (vec < 2) ? 128 : 64;
    float s0 = 0.f, s1 = 0.f;
    for (int c = 0; c < hl; c += 4) {
      float4 wv = *(const float4*)(Wr + c);
      float4 a4 = *(const float4*)(av + c);
      s0 += wv.x * a4.x + wv.y * a4.y + wv.z * a4.z + wv.w * a4.w;
    }
    for (int c = 0; c < hl; c += 4) {
      float4 wv = *(const float4*)(Wr + hl + c);
      float4 a4 = *(const float4*)(av + hl + c);
      s1 += wv.x * a4.x + wv.y * a4.y + wv.z * a4.z + wv.w * a4.w;
    }
    op[2 * k] = s0;
    op[2 * k + 1] = s1;
  }
}

// ---- CSR offsets: block-local scan + atomic block base.
// roff is NOT globally monotone — consumers use end = roff[i] + deg[i].
__global__ void k_offsets(const int* __restrict__ deg, int* __restrict__ gbase,
                          int* __restrict__ roff, float* __restrict__ dinv) {
  __shared__ int s[256];
  __shared__ int base;
  int t = threadIdx.x;
  int i = blockIdx.x * 256 + t;
  int v = (i < N_NODES) ? deg[i] : 0;
  s[t] = v;
  __syncthreads();
  for (int o = 1; o < 256; o <<= 1) {
    int x = (t >= o) ? s[t - o] : 0;
    __syncthreads();
    s[t] += x;
    __syncthreads();
  }
  if (t == 255) base = atomicAdd(gbase, s[255]);
  __syncthreads();
  int off = base + s[t] - v;
  if (i < N_NODES) {
    roff[i] = off;
    dinv[i] = rsqrtf((float)v + 1.f);
  }
}
// fill CSR slots, ATOMIC-FREE: slot = roff[d] + pos (pos captured in k_convert).
__global__ void k_fill(const int2* __restrict__ eord, const int* __restrict__ roff,
                       int2* __restrict__ aen, const float* __restrict__ dinv) {
  int i = blockIdx.x * 256 + threadIdx.x;
  if (i < N_EDGES) {
    int2 ep = eord[i];
    int s = ep.x;
    int d = ((unsigned)ep.y) >> 16;
    int pos = ep.y & 0xffff;
    aen[roff[d] + pos] = make_int2(s, __float_as_int(dinv[s]));
  }
}

// ---------------- MFMA GEMM: Hb[n,128] = bf16( X[n,128] @ W[128,128] ) --------
// W in registers, A staged in LDS, acc held across all 4 row-tiles, LDS repack
// epilogue -> uint4 stores.
__global__ __launch_bounds__(256, 4) void gemm_mfma(const float* __restrict__ X,
                                                    const unsigned short* __restrict__ Wt,
                                                    unsigned short* __restrict__ Hb) {
  __shared__ __align__(16) short smem[64 * 136];
  int tid = threadIdx.x;
  int row0 = blockIdx.x * 64;
  for (int i = tid; i < 2048; i += 256) {
    int r = i >> 5;
    int k4 = (i & 31) * 4;
    int row = row0 + r;
    float4 v = make_float4(0.f, 0.f, 0.f, 0.f);
    if (row < N_NODES) v = *(const float4*)(X + (size_t)row * 128 + k4);
    uint2 p;
    p.x = (unsigned int)f2b(v.x) | ((unsigned int)f2b(v.y) << 16);
    p.y = (unsigned int)f2b(v.z) | ((unsigned int)f2b(v.w) << 16);
    *(uint2*)&smem[r * 136 + k4] = p;
  }
  int wave = tid >> 6, lane = tid & 63;
  int m = lane & 15, quad = lane >> 4;
  int c0 = wave * 32;
  bf16x8 b[2][4];
#pragma unroll
  for (int ct = 0; ct < 2; ++ct) {
    const unsigned short* wp = Wt + (size_t)(c0 + ct * 16 + m) * 128 + quad * 8;
#pragma unroll
    for (int kk = 0; kk < 4; ++kk) b[ct][kk] = *(const bf16x8*)(wp + kk * 32);
  }
  __syncthreads();
  f32x4 acc[4][2];
#pragma unroll
  for (int rt = 0; rt < 4; ++rt)
#pragma unroll
    for (int ct = 0; ct < 2; ++ct) acc[rt][ct] = (f32x4){0.f, 0.f, 0.f, 0.f};
#pragma unroll
  for (int rt = 0; rt < 4; ++rt) {
    bf16x8 a[4];
#pragma unroll
    for (int kk = 0; kk < 4; ++kk)
      a[kk] = *(const bf16x8*)&smem[(rt * 16 + m) * 136 + kk * 32 + quad * 8];
#pragma unroll
    for (int ct = 0; ct < 2; ++ct)
#pragma unroll
      for (int kk = 0; kk < 4; ++kk)
        acc[rt][ct] = __builtin_amdgcn_mfma_f32_16x16x32_bf16(a[kk], b[ct][kk], acc[rt][ct], 0, 0, 0);
  }
  __syncthreads();  // all waves done reading A
#pragma unroll
  for (int rt = 0; rt < 4; ++rt)
#pragma unroll
    for (int ct = 0; ct < 2; ++ct)
#pragma unroll
      for (int reg = 0; reg < 4; ++reg)
        smem[(rt * 16 + quad * 4 + reg) * 128 + c0 + ct * 16 + m] = (short)f2b(acc[rt][ct][reg]);
  __syncthreads();
  for (int i = tid; i < 1024; i += 256) {
    int row = row0 + (i >> 4);
    if (row < N_NODES)
      *(uint4*)((char*)Hb + (size_t)row0 * 256 + (size_t)i * 16) =
          *(uint4*)((char*)smem + (size_t)i * 16);
  }
}

// -------- K=256 MFMA GEMM + bias+relu: G[n,128] = relu(Q[n,256]@Wt + b) ----
__global__ __launch_bounds__(256, 4) void gemm_k256(const unsigned short* __restrict__ Q,
                                                    const unsigned short* __restrict__ Wt,
                                                    const float* __restrict__ bias,
                                                    unsigned short* __restrict__ G) {
  __shared__ __align__(16) short smem[64 * 136];
  int tid = threadIdx.x;
  int row0 = blockIdx.x * 64;
  int wave = tid >> 6, lane = tid & 63;
  int m = lane & 15, quad = lane >> 4;
  int c0 = wave * 32;
  f32x4 acc[4][2];
#pragma unroll
  for (int rt = 0; rt < 4; ++rt)
#pragma unroll
    for (int ct = 0; ct < 2; ++ct) acc[rt][ct] = (f32x4){0.f, 0.f, 0.f, 0.f};
#pragma unroll
  for (int half = 0; half < 2; ++half) {
    if (half) __syncthreads();
    for (int i = tid; i < 2048; i += 256) {
      int r = i >> 5;
      int k4 = (i & 31) * 4;
      int row = row0 + r;
      uint2 p = make_uint2(0u, 0u);
      if (row < N_NODES) p = *(const uint2*)(Q + (size_t)row * 256 + half * 128 + k4);
      *(uint2*)&smem[r * 136 + k4] = p;
    }
    bf16x8 b[2][4];
#pragma unroll
    for (int ct = 0; ct < 2; ++ct) {
      const unsigned short* wp =
          Wt + (size_t)(c0 + ct * 16 + m) * 256 + half * 128 + quad * 8;
#pragma unroll
      for (int kk = 0; kk < 4; ++kk) b[ct][kk] = *(const bf16x8*)(wp + kk * 32);
    }
    __syncthreads();
#pragma unroll
    for (int rt = 0; rt < 4; ++rt) {
      bf16x8 a[4];
#pragma unroll
      for (int kk = 0; kk < 4; ++kk)
        a[kk] = *(const bf16x8*)&smem[(rt * 16 + m) * 136 + kk * 32 + quad * 8];
#pragma unroll
      for (int ct = 0; ct < 2; ++ct)
#pragma unroll
        for (int kk = 0; kk < 4; ++kk)
          acc[rt][ct] =
              __builtin_amdgcn_mfma_f32_16x16x32_bf16(a[kk], b[ct][kk], acc[rt][ct], 0, 0, 0);
    }
  }
  __syncthreads();
  float bv[2];
#pragma unroll
  for (int ct = 0; ct < 2; ++ct) bv[ct] = bias[c0 + ct * 16 + m];
#pragma unroll
  for (int rt = 0; rt < 4; ++rt)
#pragma unroll
    for (int ct = 0; ct < 2; ++ct)
#pragma unroll
      for (int reg = 0; reg < 4; ++reg)
        smem[(rt * 16 + quad * 4 + reg) * 128 + c0 + ct * 16 + m] =
            (short)f2b(fmaxf(acc[rt][ct][reg] + bv[ct], 0.f));
  __syncthreads();
  for (int i = tid; i < 1024; i += 256) {
    int row = row0 + (i >> 4);
    if (row < N_NODES)
      *(uint4*)((char*)G + (size_t)row0 * 256 + (size_t)i * 16) =
          *(uint4*)((char*)smem + (size_t)i * 16);
  }
}

// -------- Fused GCN2+GAT2-projection double GEMM:
// P2 = relu(BN(AG @ W2)) (LDS-resident) ; Q2 = P2 @ WG2 ; als/ald = P2 @ was/wad.
__global__ __launch_bounds__(256, 4) void gemm_gcn2_gat2(
    const unsigned short* __restrict__ AG, const unsigned short* __restrict__ Wt2,
    const float* __restrict__ sc, const float* __restrict__ sh,
    const unsigned short* __restrict__ WtG2,
    const float* __restrict__ was, const float* __restrict__ wad,
    float* __restrict__ als, float* __restrict__ ald,
    unsigned short* __restrict__ Q2) {
  __shared__ __align__(16) short smA[64 * 136];
  __shared__ __align__(16) short smB[64 * 136];
  int tid = threadIdx.x;
  int row0 = blockIdx.x * 64;
  for (int i = tid; i < 1024; i += 256) {
    int r = i >> 4;
    int k8 = (i & 15) * 8;
    int row = row0 + r;
    uint4 p = make_uint4(0u, 0u, 0u, 0u);
    if (row < N_NODES) p = *(const uint4*)(AG + (size_t)row * 128 + k8);
    *(uint4*)&smA[r * 136 + k8] = p;
  }
  int wave = tid >> 6, lane = tid & 63;
  int m = lane & 15, quad = lane >> 4;
  int c0 = wave * 32;
  bf16x8 b1[2][4];
#pragma unroll
  for (int ct = 0; ct < 2; ++ct) {
    const unsigned short* wp = Wt2 + (size_t)(c0 + ct * 16 + m) * 128 + quad * 8;
#pragma unroll
    for (int kk = 0; kk < 4; ++kk) b1[ct][kk] = *(const bf16x8*)(wp + kk * 32);
  }
  __syncthreads();
  f32x4 acc[4][2];
#pragma unroll
  for (int rt = 0; rt < 4; ++rt)
#pragma unroll
    for (int ct = 0; ct < 2; ++ct) acc[rt][ct] = (f32x4){0.f, 0.f, 0.f, 0.f};
#pragma unroll
  for (int rt = 0; rt < 4; ++rt) {
    bf16x8 a[4];
#pragma unroll
    for (int kk = 0; kk < 4; ++kk)
      a[kk] = *(const bf16x8*)&smA[(rt * 16 + m) * 136 + kk * 32 + quad * 8];
#pragma unroll
    for (int ct = 0; ct < 2; ++ct)
#pragma unroll
      for (int kk = 0; kk < 4; ++kk)
        acc[rt][ct] = __builtin_amdgcn_mfma_f32_16x16x32_bf16(a[kk], b1[ct][kk], acc[rt][ct], 0, 0, 0);
  }
  float scv[2], shv[2];
#pragma unroll
  for (int ct = 0; ct < 2; ++ct) {
    scv[ct] = sc[c0 + ct * 16 + m];
    shv[ct] = sh[c0 + ct * 16 + m];
  }
#pragma unroll
  for (int rt = 0; rt < 4; ++rt)
#pragma unroll
    for (int ct = 0; ct < 2; ++ct)
#pragma unroll
      for (int reg = 0; reg < 4; ++reg)
        smB[(rt * 16 + quad * 4 + reg) * 136 + c0 + ct * 16 + m] =
            (short)f2b(fmaxf(fmaf(acc[rt][ct][reg], scv[ct], shv[ct]), 0.f));
  __syncthreads();  // P2 complete before cross-wave reads
  bf16x8 b2[2][4];
#pragma unroll
  for (int ct = 0; ct < 2; ++ct) {
    const unsigned short* wp = WtG2 + (size_t)(c0 + ct * 16 + m) * 128 + quad * 8;
#pragma unroll
    for (int kk = 0; kk < 4; ++kk) b2[ct][kk] = *(const bf16x8*)(wp + kk * 32);
  }
  f32x4 acc2[4][2];
#pragma unroll
  for (int rt = 0; rt < 4; ++rt)
#pragma unroll
    for (int ct = 0; ct < 2; ++ct) acc2[rt][ct] = (f32x4){0.f, 0.f, 0.f, 0.f};
#pragma unroll
  for (int rt = 0; rt < 4; ++rt) {
    bf16x8 a[4];
#pragma unroll
    for (int kk = 0; kk < 4; ++kk)
      a[kk] = *(const bf16x8*)&smB[(rt * 16 + m) * 136 + kk * 32 + quad * 8];
#pragma unroll
    for (int ct = 0; ct < 2; ++ct)
#pragma unroll
      for (int kk = 0; kk < 4; ++kk)
        acc2[rt][ct] = __builtin_amdgcn_mfma_f32_16x16x32_bf16(a[kk], b2[ct][kk], acc2[rt][ct], 0, 0, 0);
  }
  // GAT2 logits from the LDS P2 tile: wave handles rows wave*16..+15, 4 lanes/row
  {
    int rloc = wave * 16 + (lane >> 2);
    int k0 = (lane & 3) * 32;
    float s0 = 0.f, s1 = 0.f, d0 = 0.f, d1 = 0.f;
#pragma unroll
    for (int c = 0; c < 32; c += 2) {
      unsigned u = *(const unsigned*)&smB[rloc * 136 + k0 + c];
      float x0 = blo(u), x1 = bhi(u);
      float4 ws4 = *(const float4*)(was + 2 * (k0 + c));
      float4 wd4 = *(const float4*)(wad + 2 * (k0 + c));
      s0 = fmaf(x0, ws4.x, s0); s1 = fmaf(x0, ws4.y, s1);
      s0 = fmaf(x1, ws4.z, s0); s1 = fmaf(x1, ws4.w, s1);
      d0 = fmaf(x0, wd4.x, d0); d1 = fmaf(x0, wd4.y, d1);
      d0 = fmaf(x1, wd4.z, d0); d1 = fmaf(x1, wd4.w, d1);
    }
#pragma unroll
    for (int mask = 1; mask <= 2; mask <<= 1) {
      s0 += __shfl_xor(s0, mask, 64);
      s1 += __shfl_xor(s1, mask, 64);
      d0 += __shfl_xor(d0, mask, 64);
      d1 += __shfl_xor(d1, mask, 64);
    }
    int row = row0 + rloc;
    if ((lane & 3) == 0 && row < N_NODES) {
      *(float2*)(als + 2 * row) = make_float2(s0, s1);
      *(float2*)(ald + 2 * row) = make_float2(d0, d1);
    }
  }
#pragma unroll
  for (int rt = 0; rt < 4; ++rt)
#pragma unroll
    for (int ct = 0; ct < 2; ++ct)
#pragma unroll
      for (int reg = 0; reg < 4; ++reg)
        smA[(rt * 16 + quad * 4 + reg) * 128 + c0 + ct * 16 + m] =
            (short)f2b(acc2[rt][ct][reg]);
  __syncthreads();
  for (int i = tid; i < 1024; i += 256) {
    int row = row0 + (i >> 4);
    if (row < N_NODES)
      *(uint4*)((char*)Q2 + (size_t)row0 * 256 + (size_t)i * 16) =
          *(uint4*)((char*)smA + (size_t)i * 16);
  }
}

// ---- GCN aggregation: 4 nodes/wave; lane-distributed edge meta, 8 gathers in
// ---- flight, prefetch. MODE 0: BN+relu+logits epilogue. MODE 1: raw agg out.
template <int MODE>
__global__ __launch_bounds__(256) void gcn_pull(const unsigned short* __restrict__ Hb,
                                                const int2* __restrict__ aen,
                                                const int* __restrict__ roff,
                                                const int* __restrict__ deg,
                                                const float* __restrict__ dinv,
                                                const float* __restrict__ sc,
                                                const float* __restrict__ sh,
                                                const float* __restrict__ was,
                                                const float* __restrict__ wad,
                                                float* __restrict__ als,
                                                float* __restrict__ ald,
                                                unsigned short* __restrict__ out) {
  int wv = (blockIdx.x * 256 + threadIdx.x) >> 6;
  int lane = threadIdx.x & 63;
  int q4 = lane >> 4, l16 = lane & 15;
  int qb = lane & 48, l7 = lane & 7;
  int i = 4 * wv + q4;
  if (i >= N_NODES) return;
  int off = roff[i], end = off + deg[i];
  float di = dinv[i];
  uint4 u = *(const uint4*)((const char*)Hb + (unsigned)i * 256u + l16 * 16u);
  float a0 = blo(u.x) * di, a1 = bhi(u.x) * di;
  float a2 = blo(u.y) * di, a3 = bhi(u.y) * di;
  float a4 = blo(u.z) * di, a5 = bhi(u.z) * di;
  float a6 = blo(u.w) * di, a7 = bhi(u.w) * di;  // self-loop
  int j = off;
  int nfull = (end - off) >> 3;
  int2 ae = make_int2(i, 0);
  if (l7 < end - j) ae = aen[j + l7];
  for (int t = 0; t < nfull; ++t) {
    int ss[8];
#pragma unroll
    for (int k = 0; k < 8; ++k) ss[k] = __shfl(ae.x, qb + k, 64);
    float ww[8];
#pragma unroll
    for (int k = 0; k < 8; ++k) ww[k] = __shfl(__int_as_float(ae.y), qb + k, 64);
    uint4 vv[8];
#pragma unroll
    for (int k = 0; k < 8; ++k)
      vv[k] = *(const uint4*)((const char*)Hb + (unsigned)ss[k] * 256u + l16 * 16u);
    j += 8;
    if (l7 < end - j) ae = aen[j + l7];  // prefetch next batch
#pragma unroll
    for (int k = 0; k < 8; ++k) {
      a0 = fmaf(blo(vv[k].x), ww[k], a0); a1 = fmaf(bhi(vv[k].x), ww[k], a1);
      a2 = fmaf(blo(vv[k].y), ww[k], a2); a3 = fmaf(bhi(vv[k].y), ww[k], a3);
      a4 = fmaf(blo(vv[k].z), ww[k], a4); a5 = fmaf(bhi(vv[k].z), ww[k], a5);
      a6 = fmaf(blo(vv[k].w), ww[k], a6); a7 = fmaf(bhi(vv[k].w), ww[k], a7);
    }
  }
  int rem = end - j;
  if (rem) {
    int ss[8];
#pragma unroll
    for (int k = 0; k < 8; ++k) ss[k] = __shfl(ae.x, qb + k, 64);
    float ww[8];
#pragma unroll
    for (int k = 0; k < 8; ++k) ww[k] = __shfl(__int_as_float(ae.y), qb + k, 64);
    uint4 vv[8];
#pragma unroll
    for (int k = 0; k < 8; ++k)
      if (k < rem)
        vv[k] = *(const uint4*)((const char*)Hb + (unsigned)ss[k] * 256u + l16 * 16u);
#pragma unroll
    for (int k = 0; k < 8; ++k)
      if (k < rem) {
        a0 = fmaf(blo(vv[k].x), ww[k], a0); a1 = fmaf(bhi(vv[k].x), ww[k], a1);
        a2 = fmaf(blo(vv[k].y), ww[k], a2); a3 = fmaf(bhi(vv[k].y), ww[k], a3);
        a4 = fmaf(blo(vv[k].z), ww[k], a4); a5 = fmaf(bhi(vv[k].z), ww[k], a5);
        a6 = fmaf(blo(vv[k].w), ww[k], a6); a7 = fmaf(bhi(vv[k].w), ww[k], a7);
      }
  }
  if constexpr (MODE == 1) {
    uint4 pw;
    pw.x = (unsigned int)f2b(a0 * di) | ((unsigned int)f2b(a1 * di) << 16);
    pw.y = (unsigned int)f2b(a2 * di) | ((unsigned int)f2b(a3 * di) << 16);
    pw.z = (unsigned int)f2b(a4 * di) | ((unsigned int)f2b(a5 * di) << 16);
    pw.w = (unsigned int)f2b(a6 * di) | ((unsigned int)f2b(a7 * di) << 16);
    *(uint4*)(out + (size_t)i * 128 + l16 * 8) = pw;
  } else {
    int c0 = l16 * 8;
    float4 sca = *(const float4*)(sc + c0), scb = *(const float4*)(sc + c0 + 4);
    float4 sha = *(const float4*)(sh + c0), shb = *(const float4*)(sh + c0 + 4);
    float t0 = fmaxf(fmaf(a0 * di, sca.x, sha.x), 0.f);
    float t1 = fmaxf(fmaf(a1 * di, sca.y, sha.y), 0.f);
    float t2 = fmaxf(fmaf(a2 * di, sca.z, sha.z), 0.f);
    float t3 = fmaxf(fmaf(a3 * di, sca.w, sha.w), 0.f);
    float t4 = fmaxf(fmaf(a4 * di, scb.x, shb.x), 0.f);
    float t5 = fmaxf(fmaf(a5 * di, scb.y, shb.y), 0.f);
    float t6 = fmaxf(fmaf(a6 * di, scb.z, shb.z), 0.f);
    float t7 = fmaxf(fmaf(a7 * di, scb.w, shb.w), 0.f);
    float4 w0 = *(const float4*)(was + 2 * c0);
    float4 w1 = *(const float4*)(was + 2 * c0 + 4);
    float4 w2 = *(const float4*)(was + 2 * c0 + 8);
    float4 w3 = *(const float4*)(was + 2 * c0 + 12);
    float sl0 = t0 * w0.x + t1 * w0.z + t2 * w1.x + t3 * w1.z +
                t4 * w2.x + t5 * w2.z + t6 * w3.x + t7 * w3.z;
    float sl1 = t0 * w0.y + t1 * w0.w + t2 * w1.y + t3 * w1.w +
                t4 * w2.y + t5 * w2.w + t6 * w3.y + t7 * w3.w;
    w0 = *(const float4*)(wad + 2 * c0);
    w1 = *(const float4*)(wad + 2 * c0 + 4);
    w2 = *(const float4*)(wad + 2 * c0 + 8);
    w3 = *(const float4*)(wad + 2 * c0 + 12);
    float dl0 = t0 * w0.x + t1 * w0.z + t2 * w1.x + t3 * w1.z +
                t4 * w2.x + t5 * w2.z + t6 * w3.x + t7 * w3.z;
    float dl1 = t0 * w0.y + t1 * w0.w + t2 * w1.y + t3 * w1.w +
                t4 * w2.y + t5 * w2.w + t6 * w3.y + t7 * w3.w;
#pragma unroll
    for (int mask = 1; mask <= 8; mask <<= 1) {
      sl0 += __shfl_xor(sl0, mask, 64);
      sl1 += __shfl_xor(sl1, mask, 64);
      dl0 += __shfl_xor(dl0, mask, 64);
      dl1 += __shfl_xor(dl1, mask, 64);
    }
    if (l16 == 0) {
      *(float2*)(als + 2 * i) = make_float2(sl0, sl1);
      *(float2*)(ald + 2 * i) = make_float2(dl0, dl1);
    }
    uint4 pw;
    pw.x = (unsigned int)f2b(t0) | ((unsigned int)f2b(t1) << 16);
    pw.y = (unsigned int)f2b(t2) | ((unsigned int)f2b(t3) << 16);
    pw.z = (unsigned int)f2b(t4) | ((unsigned int)f2b(t5) << 16);
    pw.w = (unsigned int)f2b(t6) | ((unsigned int)f2b(t7) << 16);
    *(uint4*)(out + (size_t)i * 128 + l16 * 8) = pw;
  }
}

// -------- GAT-1 aggregation over P (pre-GEMM, 256B rows): one row read per
// -------- edge serves BOTH heads. Q[i] = [r0*agg0 | r1*agg1], r_h=0.5/den_h.
__global__ __launch_bounds__(256) void gat1_pull(const unsigned short* __restrict__ P,
                                                 const int2* __restrict__ aen,
                                                 const int* __restrict__ roff,
                                                 const int* __restrict__ deg,
                                                 const float* __restrict__ als,
                                                 const float* __restrict__ ald,
                                                 unsigned short* __restrict__ Q) {
  int wv = (blockIdx.x * 256 + threadIdx.x) >> 6;
  int lane = threadIdx.x & 63;
  int q4 = lane >> 4, l16 = lane & 15;
  int qb = lane & 48, l7 = lane & 7;
  int i = 4 * wv + q4;
  if (i >= N_NODES) return;
  int off = roff[i], end = off + deg[i];
  float2 dif = *(const float2*)(ald + 2 * i);
  float p0 = 0.f, p1 = 0.f;
  float g0 = 0.f, g1 = 0.f, g2 = 0.f, g3 = 0.f,
        g4 = 0.f, g5 = 0.f, g6 = 0.f, g7 = 0.f;  // head0
  float h0 = 0.f, h1 = 0.f, h2 = 0.f, h3 = 0.f,
        h4 = 0.f, h5 = 0.f, h6 = 0.f, h7 = 0.f;  // head1
  int j = off;
  int nfull = (end - off) >> 3;
  int2 ae = make_int2(i, 0);
  float2 av = make_float2(-1e30f, -1e30f);
  if (l7 < end - j) {
    ae = aen[j + l7];
    av = *(const float2*)(als + 2 * ae.x);
  }
  for (int t = 0; t < nfull; ++t) {
    int ss[8];
#pragma unroll
    for (int k = 0; k < 8; ++k) ss[k] = __shfl(ae.x, qb + k, 64);
    uint4 vv[8];
#pragma unroll
    for (int k = 0; k < 8; ++k)
      vv[k] = *(const uint4*)((const char*)P + (unsigned)ss[k] * 256u + l16 * 16u);
    float q0 = __expf(leaky(av.x + dif.x));
    float q1 = __expf(leaky(av.y + dif.y));
    j += 8;
    if (l7 < end - j) {
      ae = aen[j + l7];
      av = *(const float2*)(als + 2 * ae.x);
    }
#pragma unroll
    for (int k = 0; k < 8; ++k) {
      float b0 = __shfl(q0, qb + k, 64);
      float b1 = __shfl(q1, qb + k, 64);
      p0 += b0; p1 += b1;
      float c0 = blo(vv[k].x), c1 = bhi(vv[k].x);
      float c2 = blo(vv[k].y), c3 = bhi(vv[k].y);
      float c4 = blo(vv[k].z), c5 = bhi(vv[k].z);
      float c6 = blo(vv[k].w), c7 = bhi(vv[k].w);
      g0 = fmaf(b0, c0, g0); h0 = fmaf(b1, c0, h0);
      g1 = fmaf(b0, c1, g1); h1 = fmaf(b1, c1, h1);
      g2 = fmaf(b0, c2, g2); h2 = fmaf(b1, c2, h2);
      g3 = fmaf(b0, c3, g3); h3 = fmaf(b1, c3, h3);
      g4 = fmaf(b0, c4, g4); h4 = fmaf(b1, c4, h4);
      g5 = fmaf(b0, c5, g5); h5 = fmaf(b1, c5, h5);
      g6 = fmaf(b0, c6, g6); h6 = fmaf(b1, c6, h6);
      g7 = fmaf(b0, c7, g7); h7 = fmaf(b1, c7, h7);
    }
  }
  int rem = end - j;
  if (rem) {
    int ss[8];
#pragma unroll
    for (int k = 0; k < 8; ++k) ss[k] = __shfl(ae.x, qb + k, 64);
    uint4 vv[8];
#pragma unroll
    for (int k = 0; k < 8; ++k)
      if (k < rem)
        vv[k] = *(const uint4*)((const char*)P + (unsigned)ss[k] * 256u + l16 * 16u);
    float q0 = __expf(leaky(av.x + dif.x));
    float q1 = __expf(leaky(av.y + dif.y));
#pragma unroll
    for (int k = 0; k < 8; ++k)
      if (k < rem) {
        float b0 = __shfl(q0, qb + k, 64);
        float b1 = __shfl(q1, qb + k, 64);
        p0 += b0; p1 += b1;
        float c0 = blo(vv[k].x), c1 = bhi(vv[k].x);
        float c2 = blo(vv[k].y), c3 = bhi(vv[k].y);
        float c4 = blo(vv[k].z), c5 = bhi(vv[k].z);
        float c6 = blo(vv[k].w), c7 = bhi(vv[k].w);
        g0 = fmaf(b0, c0, g0); h0 = fmaf(b1, c0, h0);
        g1 = fmaf(b0, c1, g1); h1 = fmaf(b1, c1, h1);
        g2 = fmaf(b0, c2, g2); h2 = fmaf(b1, c2, h2);
        g3 = fmaf(b0, c3, g3); h3 = fmaf(b1, c3, h3);
        g4 = fmaf(b0, c4, g4); h4 = fmaf(b1, c4, h4);
        g5 = fmaf(b0, c5, g5); h5 = fmaf(b1, c5, h5);
        g6 = fmaf(b0, c6, g6); h6 = fmaf(b1, c6, h6);
        g7 = fmaf(b0, c7, g7); h7 = fmaf(b1, c7, h7);
      }
  }
  float2 ai = *(const float2*)(als + 2 * i);
  float es0 = __expf(leaky(ai.x + dif.x));
  float es1 = __expf(leaky(ai.y + dif.y));
  float r0 = 0.5f / (p0 + es0);
  float r1 = 0.5f / (p1 + es1);
  uint4 u = *(const uint4*)((const char*)P + (unsigned)i * 256u + l16 * 16u);
  float c0 = blo(u.x), c1 = bhi(u.x), c2 = blo(u.y), c3 = bhi(u.y);
  float c4 = blo(u.z), c5 = bhi(u.z), c6 = blo(u.w), c7 = bhi(u.w);
  g0 = (g0 + es0 * c0) * r0; g1 = (g1 + es0 * c1) * r0;
  g2 = (g2 + es0 * c2) * r0; g3 = (g3 + es0 * c3) * r0;
  g4 = (g4 + es0 * c4) * r0; g5 = (g5 + es0 * c5) * r0;
  g6 = (g6 + es0 * c6) * r0; g7 = (g7 + es0 * c7) * r0;
  h0 = (h0 + es1 * c0) * r1; h1 = (h1 + es1 * c1) * r1;
  h2 = (h2 + es1 * c2) * r1; h3 = (h3 + es1 * c3) * r1;
  h4 = (h4 + es1 * c4) * r1; h5 = (h5 + es1 * c5) * r1;
  h6 = (h6 + es1 * c6) * r1; h7 = (h7 + es1 * c7) * r1;
  uint4 pw;
  pw.x = (unsigned int)f2b(g0) | ((unsigned int)f2b(g1) << 16);
  pw.y = (unsigned int)f2b(g2) | ((unsigned int)f2b(g3) << 16);
  pw.z = (unsigned int)f2b(g4) | ((unsigned int)f2b(g5) << 16);
  pw.w = (unsigned int)f2b(g6) | ((unsigned int)f2b(g7) << 16);
  *(uint4*)(Q + (size_t)i * 256 + l16 * 8) = pw;
  pw.x = (unsigned int)f2b(h0) | ((unsigned int)f2b(h1) << 16);
  pw.y = (unsigned int)f2b(h2) | ((unsigned int)f2b(h3) << 16);
  pw.z = (unsigned int)f2b(h4) | ((unsigned int)f2b(h5) << 16);
  pw.w = (unsigned int)f2b(h6) | ((unsigned int)f2b(h7) << 16);
  *(uint4*)(Q + (size_t)i * 256 + 128 + l16 * 8) = pw;
}

// ---- GAT HD=64 + fused log_softmax: 4 nodes/wave (16 lanes x 16B = 256B row).
__global__ __launch_bounds__(256) void gat_pull64_lsm(const unsigned short* __restrict__ Hb,
                                                      const int2* __restrict__ aen,
                                                      const int* __restrict__ roff,
                                                      const int* __restrict__ deg,
                                                      const float* __restrict__ als,
                                                      const float* __restrict__ ald,
                                                      const float* __restrict__ bias,
                                                      float* __restrict__ out) {
  int wv = (blockIdx.x * 256 + threadIdx.x) >> 6;
  int lane = threadIdx.x & 63;
  int q4 = lane >> 4, l16 = lane & 15;
  int qb = lane & 48, l7 = lane & 7;
  int hh = l16 >> 3, p8 = l16 & 7;
  int i = 4 * wv + q4;
  if (i >= N_NODES) return;
  int off = roff[i], end = off + deg[i];
  unsigned cb2 = (unsigned)(hh * 64 + 8 * p8) * 2u;
  float2 dd = *(const float2*)(ald + 2 * i);
  float p = 0.f;
  float acc0 = 0.f, acc1 = 0.f, acc2 = 0.f, acc3 = 0.f;
  float acc4 = 0.f, acc5 = 0.f, acc6 = 0.f, acc7 = 0.f;
  int j = off;
  int nfull = (end - off) >> 3;
  int2 ae = make_int2(i, 0);
  float2 av = make_float2(-1e30f, -1e30f);
  if (l7 < end - j) {
    ae = aen[j + l7];
    av = *(const float2*)(als + 2 * ae.x);
  }
  for (int t = 0; t < nfull; ++t) {
    int ss[8];
#pragma unroll
    for (int k = 0; k < 8; ++k) ss[k] = __shfl(ae.x, qb + k, 64);
    uint4 vv[8];
#pragma unroll
    for (int k = 0; k < 8; ++k)
      vv[k] = *(const uint4*)((const char*)Hb + (unsigned)ss[k] * 256u + cb2);
    float q0 = __expf(leaky(av.x + dd.x));
    float q1 = __expf(leaky(av.y + dd.y));
    j += 8;
    if (l7 < end - j) {
      ae = aen[j + l7];
      av = *(const float2*)(als + 2 * ae.x);
    }
#pragma unroll
    for (int k = 0; k < 8; ++k) {
      float b0 = __shfl(q0, qb + k, 64);
      float b1 = __shfl(q1, qb + k, 64);
      float q = hh ? b1 : b0;
      p += q;
      acc0 = fmaf(q, blo(vv[k].x), acc0); acc1 = fmaf(q, bhi(vv[k].x), acc1);
      acc2 = fmaf(q, blo(vv[k].y), acc2); acc3 = fmaf(q, bhi(vv[k].y), acc3);
      acc4 = fmaf(q, blo(vv[k].z), acc4); acc5 = fmaf(q, bhi(vv[k].z), acc5);
      acc6 = fmaf(q, blo(vv[k].w), acc6); acc7 = fmaf(q, bhi(vv[k].w), acc7);
    }
  }
  int rem = end - j;
  if (rem) {
    int ss[8];
#pragma unroll
    for (int k = 0; k < 8; ++k) ss[k] = __shfl(ae.x, qb + k, 64);
    uint4 vv[8];
#pragma unroll
    for (int k = 0; k < 8; ++k)
      if (k < rem)
        vv[k] = *(const uint4*)((const char*)Hb + (unsigned)ss[k] * 256u + cb2);
    float q0 = __expf(leaky(av.x + dd.x));
    float q1 = __expf(leaky(av.y + dd.y));
#pragma unroll
    for (int k = 0; k < 8; ++k)
      if (k < rem) {
        float b0 = __shfl(q0, qb + k, 64);
        float b1 = __shfl(q1, qb + k, 64);
        float q = hh ? b1 : b0;
        p += q;
        acc0 = fmaf(q, blo(vv[k].x), acc0); acc1 = fmaf(q, bhi(vv[k].x), acc1);
        acc2 = fmaf(q, blo(vv[k].y), acc2); acc3 = fmaf(q, bhi(vv[k].y), acc3);
        acc4 = fmaf(q, blo(vv[k].z), acc4); acc5 = fmaf(q, bhi(vv[k].z), acc5);
        acc6 = fmaf(q, blo(vv[k].w), acc6); acc7 = fmaf(q, bhi(vv[k].w), acc7);
      }
  }
  float2 ai = *(const float2*)(als + 2 * i);
  float axs = hh ? ai.y : ai.x;
  float dh = hh ? dd.y : dd.x;
  float es = __expf(leaky(axs + dh));
  float rsel = 0.5f / (p + es);
  uint4 u = *(const uint4*)((const char*)Hb + (unsigned)i * 256u + cb2);
  acc0 = (acc0 + es * blo(u.x)) * rsel; acc1 = (acc1 + es * bhi(u.x)) * rsel;
  acc2 = (acc2 + es * blo(u.y)) * rsel; acc3 = (acc3 + es * bhi(u.y)) * rsel;
  acc4 = (acc4 + es * blo(u.z)) * rsel; acc5 = (acc5 + es * bhi(u.z)) * rsel;
  acc6 = (acc6 + es * blo(u.w)) * rsel; acc7 = (acc7 + es * bhi(u.w)) * rsel;
  acc0 += __shfl_xor(acc0, 8, 64); acc1 += __shfl_xor(acc1, 8, 64);
  acc2 += __shfl_xor(acc2, 8, 64); acc3 += __shfl_xor(acc3, 8, 64);
  acc4 += __shfl_xor(acc4, 8, 64); acc5 += __shfl_xor(acc5, 8, 64);
  acc6 += __shfl_xor(acc6, 8, 64); acc7 += __shfl_xor(acc7, 8, 64);
  float4 b0 = *(const float4*)(bias + 8 * p8);
  float4 b1 = *(const float4*)(bias + 8 * p8 + 4);
  float v0 = acc0 + b0.x, v1 = acc1 + b0.y, v2 = acc2 + b0.z, v3 = acc3 + b0.w;
  float v4 = acc4 + b1.x, v5 = acc5 + b1.y, v6 = acc6 + b1.z, v7 = acc7 + b1.w;
  float mv = fmaxf(fmaxf(fmaxf(v0, v1), fmaxf(v2, v3)),
                   fmaxf(fmaxf(v4, v5), fmaxf(v6, v7)));
#pragma unroll
  for (int mm = 4; mm > 0; mm >>= 1) mv = fmaxf(mv, __shfl_xor(mv, mm, 64));
  float sv = __expf(v0 - mv) + __expf(v1 - mv) + __expf(v2 - mv) + __expf(v3 - mv) +
             __expf(v4 - mv) + __expf(v5 - mv) + __expf(v6 - mv) + __expf(v7 - mv);
#pragma unroll
  for (int mm = 4; mm > 0; mm >>= 1) sv += __shfl_xor(sv, mm, 64);
  float ls = mv + __logf(sv);
  if (hh == 0) {
    *(float4*)(out + (size_t)i * 64 + 8 * p8) =
        make_float4(v0 - ls, v1 - ls, v2 - ls, v3 - ls);
    *(float4*)(out + (size_t)i * 64 + 8 * p8 + 4) =
        make_float4(v4 - ls, v5 - ls, v6 - ls, v7 - ls);
  }
}

extern "C" void kernel_launch(void* const* d_in, const int* in_sizes, int n_in, void* d_out,
                              int out_size, void* d_ws, size_t ws_size, hipStream_t stream) {
  const float* x      = (const float*)d_in[0];
  const int* eidx     = (const int*)d_in[1];
  const float* W_gcn1 = (const float*)d_in[2];
  const float* b_gcn1 = (const float*)d_in[3];
  const float* bn1_g  = (const float*)d_in[4];
  const float* bn1_b  = (const float*)d_in[5];
  const float* bn1_m  = (const float*)d_in[6];
  const float* bn1_v  = (const float*)d_in[7];
  const float* W_gat1 = (const float*)d_in[8];
  const float* a_src1 = (const float*)d_in[9];
  const float* a_dst1 = (const float*)d_in[10];
  const float* b_gat1 = (const float*)d_in[11];
  const float* W_gcn2 = (const float*)d_in[12];
  const float* b_gcn2 = (const float*)d_in[13];
  const float* bn2_g  = (const float*)d_in[14];
  const float* bn2_b  = (const float*)d_in[15];
  const float* bn2_m  = (const float*)d_in[16];
  const float* bn2_v  = (const float*)d_in[17];
  const float* W_gat2 = (const float*)d_in[18];
  const float* a_src2 = (const float*)d_in[19];
  const float* a_dst2 = (const float*)d_in[20];
  const float* b_gat2 = (const float*)d_in[21];

  char* ws = (char*)d_ws;
  size_t o = 0;
  auto take = [&](size_t bytes) {
    char* p = ws + o;
    o = (o + bytes + 255) & ~(size_t)255;
    return p;
  };
  int* deg     = (int*)take((size_t)(N_NODES + 64) * 4);  // +1 int (gbase)
  int* gbase   = deg + N_NODES;
  int* roff    = (int*)take((size_t)N_NODES * 4);
  int2* eord   = (int2*)take((size_t)N_EDGES * 8);
  int2* aen    = (int2*)take((size_t)N_EDGES * 8);
  float* dinv  = (float*)take((size_t)N_NODES * 4);
  float* als   = (float*)take((size_t)2 * N_NODES * 4);
  float* ald   = (float*)take((size_t)2 * N_NODES * 4);
  float* sc1   = (float*)take(128 * 4);
  float* sh1   = (float*)take(128 * 4);
  float* sc2   = (float*)take(128 * 4);
  float* sh2   = (float*)take(128 * 4);
  float* was1  = (float*)take(256 * 4);
  float* wad1  = (float*)take(256 * 4);
  float* was2  = (float*)take(256 * 4);
  float* wad2  = (float*)take(256 * 4);
  unsigned short* Wt1  = (unsigned short*)take((size_t)128 * 128 * 2);
  unsigned short* WtG1 = (unsigned short*)take((size_t)128 * 256 * 2);  // stacked [c][256]
  unsigned short* Wt2  = (unsigned short*)take((size_t)128 * 128 * 2);
  unsigned short* WtG2 = (unsigned short*)take((size_t)128 * 128 * 2);
  unsigned short* Hb   = (unsigned short*)take((size_t)N_NODES * 128 * 2);
  unsigned short* Pb   = (unsigned short*)take((size_t)N_NODES * 128 * 2);
  unsigned short* Qb   = (unsigned short*)take((size_t)N_NODES * 256 * 2);
  unsigned short* Gb   = (unsigned short*)take((size_t)N_NODES * 128 * 2);
  unsigned short* AGb  = (unsigned short*)take((size_t)N_NODES * 128 * 2);
  unsigned short* Q2b  = (unsigned short*)take((size_t)N_NODES * 128 * 2);
  (void)ws_size; (void)in_sizes; (void)n_in; (void)out_size;

  int eb = (N_EDGES + 255) / 256;
  int nb = (N_NODES + 255) / 256;
  int qb = ((N_NODES + 3) / 4 + 3) / 4;    // wave per 4 nodes (pull kernels)
  int gb = (N_NODES + 63) / 64;            // MFMA-GEMM blocks

  // CSR build + prep (k_fill is atomic-free: slot captured in k_convert)
  hipMemsetAsync(deg, 0, (size_t)(N_NODES + 1) * 4, stream);
  k_convert<<<eb, 256, 0, stream>>>(eidx, deg, eord, W_gcn1, W_gat1, W_gcn2, W_gat2,
                                    Wt1, WtG1, Wt2, WtG2, b_gcn1, bn1_g, bn1_b, bn1_m, bn1_v,
                                    b_gcn2, bn2_g, bn2_b, bn2_m, bn2_v, sc1, sh1, sc2, sh2,
                                    a_src1, a_dst1, a_src2, a_dst2, was1, wad1, was2, wad2);
  k_offsets<<<nb, 256, 0, stream>>>(deg, gbase, roff, dinv);
  k_fill<<<eb, 256, 0, stream>>>(eord, roff, aen, dinv);

  // Layer pipeline:
  //  L1 GCN : gemm(x@W1) -> gcn_pull<0> (BN+relu+logits1)
  //  L2 GAT : gat1_pull (dual-head agg of P) -> gemm_k256 (stacked W, bias, relu)
  //  L3 GCN + L4 GAT proj: gcn_pull<1> (raw agg) -> fused double GEMM (+logits2)
  //  L4 GAT : gat_pull64_lsm
  gemm_mfma<<<gb, 256, 0, stream>>>(x, Wt1, Hb);
  gcn_pull<0><<<qb, 256, 0, stream>>>(Hb, aen, roff, deg, dinv, sc1, sh1, was1, wad1,
                                      als, ald, Pb);
  gat1_pull<<<qb, 256, 0, stream>>>(Pb, aen, roff, deg, als, ald, Qb);
  gemm_k256<<<gb, 256, 0, stream>>>(Qb, WtG1, b_gat1, Gb);
  gcn_pull<1><<<qb, 256, 0, stream>>>(Gb, aen, roff, deg, dinv, nullptr, nullptr,
                                      nullptr, nullptr, nullptr, nullptr, AGb);
  gemm_gcn2_gat2<<<gb, 256, 0, stream>>>(AGb, Wt2, sc2, sh2, WtG2, was2, wad2,
                                         als, ald, Q2b);
  gat_pull64_lsm<<<qb, 256, 0, stream>>>(Q2b, aen, roff, deg, als, ald, b_gat2,
                                         (float*)d_out);
}

// Round 7
// 305.716 us; speedup vs baseline: 1.1204x; 1.0279x over previous
//
#include <hip/hip_runtime.h>
#include <hip/hip_bf16.h>

#define N_NODES 50000
#define N_EDGES 600000
#define GEMM_BLOCKS 782  // (N_NODES+63)/64

typedef short bf16x8 __attribute__((ext_vector_type(8)));
typedef float f32x4 __attribute__((ext_vector_type(4)));

__device__ __forceinline__ float leaky(float e) { return fmaxf(e, 0.2f * e); }
__device__ __forceinline__ unsigned short f2b(float f) {
  __hip_bfloat16 h = __float2bfloat16(f);
  return *reinterpret_cast<unsigned short*>(&h);
}
__device__ __forceinline__ float blo(unsigned int u) { return __uint_as_float(u << 16); }
__device__ __forceinline__ float bhi(unsigned int u) { return __uint_as_float(u & 0xffff0000u); }

// ------- FUSED: [blocks 0..781] Hb = bf16(X @ W1)  (B-frags converted inline
// ------- from fp32 W1 -> no dependency on convert blocks' outputs)
// ------- [blocks 782..] edge convert + deg count + weight prep.
// The deg atomic's return value IS the CSR slot: eord[i] = {src, (d<<16)|pos}.
// WtG1 stacked [c(128)][k(256)]; was/wad = W_gat @ a_{src,dst}.
__global__ __launch_bounds__(256, 4) void k_convert_gemm(
    const int* __restrict__ e, int* __restrict__ deg, int2* __restrict__ eord,
    const float* __restrict__ X, unsigned short* __restrict__ Hb,
    const float* __restrict__ W1, const float* __restrict__ WG1,
    const float* __restrict__ W2, const float* __restrict__ WG2,
    unsigned short* __restrict__ WtG1,
    unsigned short* __restrict__ Wt2, unsigned short* __restrict__ WtG2,
    const float* b1, const float* g1, const float* be1, const float* m1,
    const float* v1, const float* b2, const float* g2, const float* be2,
    const float* m2, const float* v2, float* sc1, float* sh1,
    float* sc2, float* sh2,
    const float* as1, const float* ad1, const float* as2,
    const float* ad2, float* was1, float* wad1, float* was2, float* wad2) {
  __shared__ __align__(16) short smem[64 * 136];
  int tid = threadIdx.x;
  if (blockIdx.x < GEMM_BLOCKS) {
    // ---------------- GEMM part: Hb[n,128] = bf16( X[n,128] @ W1 ) ----------
    int row0 = blockIdx.x * 64;
    for (int i = tid; i < 2048; i += 256) {
      int r = i >> 5;
      int k4 = (i & 31) * 4;
      int row = row0 + r;
      float4 v = make_float4(0.f, 0.f, 0.f, 0.f);
      if (row < N_NODES) v = *(const float4*)(X + (size_t)row * 128 + k4);
      uint2 p;
      p.x = (unsigned int)f2b(v.x) | ((unsigned int)f2b(v.y) << 16);
      p.y = (unsigned int)f2b(v.z) | ((unsigned int)f2b(v.w) << 16);
      *(uint2*)&smem[r * 136 + k4] = p;
    }
    int wave = tid >> 6, lane = tid & 63;
    int m = lane & 15, quad = lane >> 4;
    int c0 = wave * 32;
    bf16x8 b[2][4];
#pragma unroll
    for (int ct = 0; ct < 2; ++ct) {
      int col = c0 + ct * 16 + m;
#pragma unroll
      for (int kk = 0; kk < 4; ++kk) {
        bf16x8 v;
#pragma unroll
        for (int el = 0; el < 8; ++el)
          v[el] = (short)f2b(W1[(size_t)(kk * 32 + quad * 8 + el) * 128 + col]);
        b[ct][kk] = v;
      }
    }
    __syncthreads();
    f32x4 acc[4][2];
#pragma unroll
    for (int rt = 0; rt < 4; ++rt)
#pragma unroll
      for (int ct = 0; ct < 2; ++ct) acc[rt][ct] = (f32x4){0.f, 0.f, 0.f, 0.f};
#pragma unroll
    for (int rt = 0; rt < 4; ++rt) {
      bf16x8 a[4];
#pragma unroll
      for (int kk = 0; kk < 4; ++kk)
        a[kk] = *(const bf16x8*)&smem[(rt * 16 + m) * 136 + kk * 32 + quad * 8];
#pragma unroll
      for (int ct = 0; ct < 2; ++ct)
#pragma unroll
        for (int kk = 0; kk < 4; ++kk)
          acc[rt][ct] = __builtin_amdgcn_mfma_f32_16x16x32_bf16(a[kk], b[ct][kk], acc[rt][ct], 0, 0, 0);
    }
    __syncthreads();
#pragma unroll
    for (int rt = 0; rt < 4; ++rt)
#pragma unroll
      for (int ct = 0; ct < 2; ++ct)
#pragma unroll
        for (int reg = 0; reg < 4; ++reg)
          smem[(rt * 16 + quad * 4 + reg) * 128 + c0 + ct * 16 + m] = (short)f2b(acc[rt][ct][reg]);
    __syncthreads();
    for (int i = tid; i < 1024; i += 256) {
      int row = row0 + (i >> 4);
      if (row < N_NODES)
        *(uint4*)((char*)Hb + (size_t)row0 * 256 + (size_t)i * 16) =
            *(uint4*)((char*)smem + (size_t)i * 16);
    }
    return;
  }
  // ---------------- convert part ----------------
  __shared__ int sflag;
  if (tid < 64) {  // sample odd int32 words; all-zero => int64 input
    int idx = 1 + 2 * tid * 4096;
    int v = e[idx];
    unsigned long long nz = __ballot(v != 0);
    if (tid == 0) sflag = (nz == 0ULL) ? 1 : 0;
  }
  __syncthreads();
  int f = sflag;
  int i = (blockIdx.x - GEMM_BLOCKS) * 256 + tid;
  if (i < N_EDGES) {
    int s, d;
    if (f) { s = e[2 * i]; d = e[2 * (N_EDGES + i)]; }
    else   { s = e[i];     d = e[N_EDGES + i]; }
    int pos = atomicAdd(&deg[d], 1);
    eord[i] = make_int2(s, (d << 16) | pos);  // d<65536, pos<=maxdeg (~40): safe
  }
  // fused prep (independent outputs, same index space)
  if (i < 32768) {
    int l = i;                          // WG1: l = k*256 + c8
    int k = l >> 8, c8 = l & 255;
    int head = c8 >> 7, cc = c8 & 127;
    WtG1[cc * 256 + head * 128 + k] = f2b(WG1[l]);
  } else if (i < 49152) {
    int l = i - 16384;                  // continue WG1 range [16384,32768)
    int k = l >> 8, c8 = l & 255;
    int head = c8 >> 7, cc = c8 & 127;
    WtG1[cc * 256 + head * 128 + k] = f2b(WG1[l]);
  } else if (i < 65536) {
    int l = i - 49152;
    int k = l >> 7, c = l & 127;
    Wt2[c * 128 + k] = f2b(W2[l]);
  } else if (i < 81920) {
    int l = i - 65536;
    int k = l >> 7, c = l & 127;
    WtG2[c * 128 + k] = f2b(WG2[l]);
  } else if (i < 82048) {
    int c = i - 81920;
    float s = g1[c] * rsqrtf(v1[c] + 1e-5f);
    sc1[c] = s;
    sh1[c] = (b1[c] - m1[c]) * s + be1[c];
  } else if (i < 82176) {
    int c = i - 82048;
    float s = g2[c] * rsqrtf(v2[c] + 1e-5f);
    sc2[c] = s;
    sh2[c] = (b2[c] - m2[c]) * s + be2[c];
  } else if (i < 82688) {
    // was/wad[k][h] = sum_c WG[k][h*HL+c] * a[h*HL+c]   (layout [128][2], h inner)
    int j = i - 82176;
    int k = j & 127;
    int vec = j >> 7;  // 0=was1 1=wad1 2=was2 3=wad2
    const float* Wr = (vec < 2) ? (WG1 + k * 256) : (WG2 + k * 128);
    const float* av = (vec == 0) ? as1 : (vec == 1) ? ad1 : (vec == 2) ? as2 : ad2;
    float* op = (vec == 0) ? was1 : (vec == 1) ? wad1 : (vec == 2) ? was2 : wad2;
    int hl = (vec < 2) ? 128 : 64;
    float s0 = 0.f, s1 = 0.f;
    for (int c = 0; c < hl; c += 4) {
      float4 wv = *(const float4*)(Wr + c);
      float4 a4 = *(const float4*)(av + c);
      s0 += wv.x * a4.x + wv.y * a4.y + wv.z * a4.z + wv.w * a4.w;
    }
    for (int c = 0; c < hl; c += 4) {
      float4 wv = *(const float4*)(Wr + hl + c);
      float4 a4 = *(const float4*)(av + hl + c);
      s1 += wv.x * a4.x + wv.y * a4.y + wv.z * a4.z + wv.w * a4.w;
    }
    op[2 * k] = s0;
    op[2 * k + 1] = s1;
  }
}

// ---- CSR offsets: block-local scan + atomic block base.
// roff is NOT globally monotone — consumers use end = roff[i] + deg[i].
__global__ void k_offsets(const int* __restrict__ deg, int* __restrict__ gbase,
                          int* __restrict__ roff, float* __restrict__ dinv) {
  __shared__ int s[256];
  __shared__ int base;
  int t = threadIdx.x;
  int i = blockIdx.x * 256 + t;
  int v = (i < N_NODES) ? deg[i] : 0;
  s[t] = v;
  __syncthreads();
  for (int o = 1; o < 256; o <<= 1) {
    int x = (t >= o) ? s[t - o] : 0;
    __syncthreads();
    s[t] += x;
    __syncthreads();
  }
  if (t == 255) base = atomicAdd(gbase, s[255]);
  __syncthreads();
  int off = base + s[t] - v;
  if (i < N_NODES) {
    roff[i] = off;
    dinv[i] = rsqrtf((float)v + 1.f);
  }
}
// fill CSR slots, ATOMIC-FREE: slot = roff[d] + pos (pos captured in k_convert).
__global__ void k_fill(const int2* __restrict__ eord, const int* __restrict__ roff,
                       int2* __restrict__ aen, const float* __restrict__ dinv) {
  int i = blockIdx.x * 256 + threadIdx.x;
  if (i < N_EDGES) {
    int2 ep = eord[i];
    int s = ep.x;
    int d = ((unsigned)ep.y) >> 16;
    int pos = ep.y & 0xffff;
    aen[roff[d] + pos] = make_int2(s, __float_as_int(dinv[s]));
  }
}

// -------- K=256 MFMA GEMM + bias+relu: G[n,128] = relu(Q[n,256]@Wt + b) ----
__global__ __launch_bounds__(256, 4) void gemm_k256(const unsigned short* __restrict__ Q,
                                                    const unsigned short* __restrict__ Wt,
                                                    const float* __restrict__ bias,
                                                    unsigned short* __restrict__ G) {
  __shared__ __align__(16) short smem[64 * 136];
  int tid = threadIdx.x;
  int row0 = blockIdx.x * 64;
  int wave = tid >> 6, lane = tid & 63;
  int m = lane & 15, quad = lane >> 4;
  int c0 = wave * 32;
  f32x4 acc[4][2];
#pragma unroll
  for (int rt = 0; rt < 4; ++rt)
#pragma unroll
    for (int ct = 0; ct < 2; ++ct) acc[rt][ct] = (f32x4){0.f, 0.f, 0.f, 0.f};
#pragma unroll
  for (int half = 0; half < 2; ++half) {
    if (half) __syncthreads();
    for (int i = tid; i < 1024; i += 256) {
      int r = i >> 4;
      int k8 = (i & 15) * 8;
      int row = row0 + r;
      uint4 p = make_uint4(0u, 0u, 0u, 0u);
      if (row < N_NODES) p = *(const uint4*)(Q + (size_t)row * 256 + half * 128 + k8);
      *(uint4*)&smem[r * 136 + k8] = p;
    }
    bf16x8 b[2][4];
#pragma unroll
    for (int ct = 0; ct < 2; ++ct) {
      const unsigned short* wp =
          Wt + (size_t)(c0 + ct * 16 + m) * 256 + half * 128 + quad * 8;
#pragma unroll
      for (int kk = 0; kk < 4; ++kk) b[ct][kk] = *(const bf16x8*)(wp + kk * 32);
    }
    __syncthreads();
#pragma unroll
    for (int rt = 0; rt < 4; ++rt) {
      bf16x8 a[4];
#pragma unroll
      for (int kk = 0; kk < 4; ++kk)
        a[kk] = *(const bf16x8*)&smem[(rt * 16 + m) * 136 + kk * 32 + quad * 8];
#pragma unroll
      for (int ct = 0; ct < 2; ++ct)
#pragma unroll
        for (int kk = 0; kk < 4; ++kk)
          acc[rt][ct] =
              __builtin_amdgcn_mfma_f32_16x16x32_bf16(a[kk], b[ct][kk], acc[rt][ct], 0, 0, 0);
    }
  }
  __syncthreads();
  float bv[2];
#pragma unroll
  for (int ct = 0; ct < 2; ++ct) bv[ct] = bias[c0 + ct * 16 + m];
#pragma unroll
  for (int rt = 0; rt < 4; ++rt)
#pragma unroll
    for (int ct = 0; ct < 2; ++ct)
#pragma unroll
      for (int reg = 0; reg < 4; ++reg)
        smem[(rt * 16 + quad * 4 + reg) * 128 + c0 + ct * 16 + m] =
            (short)f2b(fmaxf(acc[rt][ct][reg] + bv[ct], 0.f));
  __syncthreads();
  for (int i = tid; i < 1024; i += 256) {
    int row = row0 + (i >> 4);
    if (row < N_NODES)
      *(uint4*)((char*)G + (size_t)row0 * 256 + (size_t)i * 16) =
          *(uint4*)((char*)smem + (size_t)i * 16);
  }
}

// -------- Fused GCN2+GAT2-projection double GEMM:
// P2 = relu(BN(AG @ W2)) (LDS-resident) ; Q2 = P2 @ WG2 ; als/ald = P2 @ was/wad.
__global__ __launch_bounds__(256, 4) void gemm_gcn2_gat2(
    const unsigned short* __restrict__ AG, const unsigned short* __restrict__ Wt2,
    const float* __restrict__ sc, const float* __restrict__ sh,
    const unsigned short* __restrict__ WtG2,
    const float* __restrict__ was, const float* __restrict__ wad,
    float* __restrict__ als, float* __restrict__ ald,
    unsigned short* __restrict__ Q2) {
  __shared__ __align__(16) short smA[64 * 136];
  __shared__ __align__(16) short smB[64 * 136];
  int tid = threadIdx.x;
  int row0 = blockIdx.x * 64;
  for (int i = tid; i < 1024; i += 256) {
    int r = i >> 4;
    int k8 = (i & 15) * 8;
    int row = row0 + r;
    uint4 p = make_uint4(0u, 0u, 0u, 0u);
    if (row < N_NODES) p = *(const uint4*)(AG + (size_t)row * 128 + k8);
    *(uint4*)&smA[r * 136 + k8] = p;
  }
  int wave = tid >> 6, lane = tid & 63;
  int m = lane & 15, quad = lane >> 4;
  int c0 = wave * 32;
  bf16x8 b1[2][4];
#pragma unroll
  for (int ct = 0; ct < 2; ++ct) {
    const unsigned short* wp = Wt2 + (size_t)(c0 + ct * 16 + m) * 128 + quad * 8;
#pragma unroll
    for (int kk = 0; kk < 4; ++kk) b1[ct][kk] = *(const bf16x8*)(wp + kk * 32);
  }
  __syncthreads();
  f32x4 acc[4][2];
#pragma unroll
  for (int rt = 0; rt < 4; ++rt)
#pragma unroll
    for (int ct = 0; ct < 2; ++ct) acc[rt][ct] = (f32x4){0.f, 0.f, 0.f, 0.f};
#pragma unroll
  for (int rt = 0; rt < 4; ++rt) {
    bf16x8 a[4];
#pragma unroll
    for (int kk = 0; kk < 4; ++kk)
      a[kk] = *(const bf16x8*)&smA[(rt * 16 + m) * 136 + kk * 32 + quad * 8];
#pragma unroll
    for (int ct = 0; ct < 2; ++ct)
#pragma unroll
      for (int kk = 0; kk < 4; ++kk)
        acc[rt][ct] = __builtin_amdgcn_mfma_f32_16x16x32_bf16(a[kk], b1[ct][kk], acc[rt][ct], 0, 0, 0);
  }
  float scv[2], shv[2];
#pragma unroll
  for (int ct = 0; ct < 2; ++ct) {
    scv[ct] = sc[c0 + ct * 16 + m];
    shv[ct] = sh[c0 + ct * 16 + m];
  }
#pragma unroll
  for (int rt = 0; rt < 4; ++rt)
#pragma unroll
    for (int ct = 0; ct < 2; ++ct)
#pragma unroll
      for (int reg = 0; reg < 4; ++reg)
        smB[(rt * 16 + quad * 4 + reg) * 136 + c0 + ct * 16 + m] =
            (short)f2b(fmaxf(fmaf(acc[rt][ct][reg], scv[ct], shv[ct]), 0.f));
  __syncthreads();  // P2 complete before cross-wave reads
  bf16x8 b2[2][4];
#pragma unroll
  for (int ct = 0; ct < 2; ++ct) {
    const unsigned short* wp = WtG2 + (size_t)(c0 + ct * 16 + m) * 128 + quad * 8;
#pragma unroll
    for (int kk = 0; kk < 4; ++kk) b2[ct][kk] = *(const bf16x8*)(wp + kk * 32);
  }
  f32x4 acc2[4][2];
#pragma unroll
  for (int rt = 0; rt < 4; ++rt)
#pragma unroll
    for (int ct = 0; ct < 2; ++ct) acc2[rt][ct] = (f32x4){0.f, 0.f, 0.f, 0.f};
#pragma unroll
  for (int rt = 0; rt < 4; ++rt) {
    bf16x8 a[4];
#pragma unroll
    for (int kk = 0; kk < 4; ++kk)
      a[kk] = *(const bf16x8*)&smB[(rt * 16 + m) * 136 + kk * 32 + quad * 8];
#pragma unroll
    for (int ct = 0; ct < 2; ++ct)
#pragma unroll
      for (int kk = 0; kk < 4; ++kk)
        acc2[rt][ct] = __builtin_amdgcn_mfma_f32_16x16x32_bf16(a[kk], b2[ct][kk], acc2[rt][ct], 0, 0, 0);
  }
  // GAT2 logits from the LDS P2 tile: wave handles rows wave*16..+15, 4 lanes/row
  {
    int rloc = wave * 16 + (lane >> 2);
    int k0 = (lane & 3) * 32;
    float s0 = 0.f, s1 = 0.f, d0 = 0.f, d1 = 0.f;
#pragma unroll
    for (int c = 0; c < 32; c += 2) {
      unsigned u = *(const unsigned*)&smB[rloc * 136 + k0 + c];
      float x0 = blo(u), x1 = bhi(u);
      float4 ws4 = *(const float4*)(was + 2 * (k0 + c));
      float4 wd4 = *(const float4*)(wad + 2 * (k0 + c));
      s0 = fmaf(x0, ws4.x, s0); s1 = fmaf(x0, ws4.y, s1);
      s0 = fmaf(x1, ws4.z, s0); s1 = fmaf(x1, ws4.w, s1);
      d0 = fmaf(x0, wd4.x, d0); d1 = fmaf(x0, wd4.y, d1);
      d0 = fmaf(x1, wd4.z, d0); d1 = fmaf(x1, wd4.w, d1);
    }
#pragma unroll
    for (int mask = 1; mask <= 2; mask <<= 1) {
      s0 += __shfl_xor(s0, mask, 64);
      s1 += __shfl_xor(s1, mask, 64);
      d0 += __shfl_xor(d0, mask, 64);
      d1 += __shfl_xor(d1, mask, 64);
    }
    int row = row0 + rloc;
    if ((lane & 3) == 0 && row < N_NODES) {
      *(float2*)(als + 2 * row) = make_float2(s0, s1);
      *(float2*)(ald + 2 * row) = make_float2(d0, d1);
    }
  }
#pragma unroll
  for (int rt = 0; rt < 4; ++rt)
#pragma unroll
    for (int ct = 0; ct < 2; ++ct)
#pragma unroll
      for (int reg = 0; reg < 4; ++reg)
        smA[(rt * 16 + quad * 4 + reg) * 128 + c0 + ct * 16 + m] =
            (short)f2b(acc2[rt][ct][reg]);
  __syncthreads();
  for (int i = tid; i < 1024; i += 256) {
    int row = row0 + (i >> 4);
    if (row < N_NODES)
      *(uint4*)((char*)Q2 + (size_t)row0 * 256 + (size_t)i * 16) =
          *(uint4*)((char*)smA + (size_t)i * 16);
  }
}

// ---- GCN aggregation: 4 nodes/wave; lane-distributed edge meta, 8 gathers in
// ---- flight, prefetch. MODE 0: BN+relu+logits epilogue. MODE 1: raw agg out.
template <int MODE>
__global__ __launch_bounds__(256) void gcn_pull(const unsigned short* __restrict__ Hb,
                                                const int2* __restrict__ aen,
                                                const int* __restrict__ roff,
                                                const int* __restrict__ deg,
                                                const float* __restrict__ dinv,
                                                const float* __restrict__ sc,
                                                const float* __restrict__ sh,
                                                const float* __restrict__ was,
                                                const float* __restrict__ wad,
                                                float* __restrict__ als,
                                                float* __restrict__ ald,
                                                unsigned short* __restrict__ out) {
  int wv = (blockIdx.x * 256 + threadIdx.x) >> 6;
  int lane = threadIdx.x & 63;
  int q4 = lane >> 4, l16 = lane & 15;
  int qb = lane & 48, l7 = lane & 7;
  int i = 4 * wv + q4;
  if (i >= N_NODES) return;
  int off = roff[i], end = off + deg[i];
  float di = dinv[i];
  uint4 u = *(const uint4*)((const char*)Hb + (unsigned)i * 256u + l16 * 16u);
  float a0 = blo(u.x) * di, a1 = bhi(u.x) * di;
  float a2 = blo(u.y) * di, a3 = bhi(u.y) * di;
  float a4 = blo(u.z) * di, a5 = bhi(u.z) * di;
  float a6 = blo(u.w) * di, a7 = bhi(u.w) * di;  // self-loop
  int j = off;
  int nfull = (end - off) >> 3;
  int2 ae = make_int2(i, 0);
  if (l7 < end - j) ae = aen[j + l7];
  for (int t = 0; t < nfull; ++t) {
    int ss[8];
#pragma unroll
    for (int k = 0; k < 8; ++k) ss[k] = __shfl(ae.x, qb + k, 64);
    float ww[8];
#pragma unroll
    for (int k = 0; k < 8; ++k) ww[k] = __shfl(__int_as_float(ae.y), qb + k, 64);
    uint4 vv[8];
#pragma unroll
    for (int k = 0; k < 8; ++k)
      vv[k] = *(const uint4*)((const char*)Hb + (unsigned)ss[k] * 256u + l16 * 16u);
    j += 8;
    if (l7 < end - j) ae = aen[j + l7];  // prefetch next batch
#pragma unroll
    for (int k = 0; k < 8; ++k) {
      a0 = fmaf(blo(vv[k].x), ww[k], a0); a1 = fmaf(bhi(vv[k].x), ww[k], a1);
      a2 = fmaf(blo(vv[k].y), ww[k], a2); a3 = fmaf(bhi(vv[k].y), ww[k], a3);
      a4 = fmaf(blo(vv[k].z), ww[k], a4); a5 = fmaf(bhi(vv[k].z), ww[k], a5);
      a6 = fmaf(blo(vv[k].w), ww[k], a6); a7 = fmaf(bhi(vv[k].w), ww[k], a7);
    }
  }
  int rem = end - j;
  if (rem) {
    int ss[8];
#pragma unroll
    for (int k = 0; k < 8; ++k) ss[k] = __shfl(ae.x, qb + k, 64);
    float ww[8];
#pragma unroll
    for (int k = 0; k < 8; ++k) ww[k] = __shfl(__int_as_float(ae.y), qb + k, 64);
    uint4 vv[8];
#pragma unroll
    for (int k = 0; k < 8; ++k)
      if (k < rem)
        vv[k] = *(const uint4*)((const char*)Hb + (unsigned)ss[k] * 256u + l16 * 16u);
#pragma unroll
    for (int k = 0; k < 8; ++k)
      if (k < rem) {
        a0 = fmaf(blo(vv[k].x), ww[k], a0); a1 = fmaf(bhi(vv[k].x), ww[k], a1);
        a2 = fmaf(blo(vv[k].y), ww[k], a2); a3 = fmaf(bhi(vv[k].y), ww[k], a3);
        a4 = fmaf(blo(vv[k].z), ww[k], a4); a5 = fmaf(bhi(vv[k].z), ww[k], a5);
        a6 = fmaf(blo(vv[k].w), ww[k], a6); a7 = fmaf(bhi(vv[k].w), ww[k], a7);
      }
  }
  if constexpr (MODE == 1) {
    uint4 pw;
    pw.x = (unsigned int)f2b(a0 * di) | ((unsigned int)f2b(a1 * di) << 16);
    pw.y = (unsigned int)f2b(a2 * di) | ((unsigned int)f2b(a3 * di) << 16);
    pw.z = (unsigned int)f2b(a4 * di) | ((unsigned int)f2b(a5 * di) << 16);
    pw.w = (unsigned int)f2b(a6 * di) | ((unsigned int)f2b(a7 * di) << 16);
    *(uint4*)(out + (size_t)i * 128 + l16 * 8) = pw;
  } else {
    int c0 = l16 * 8;
    float4 sca = *(const float4*)(sc + c0), scb = *(const float4*)(sc + c0 + 4);
    float4 sha = *(const float4*)(sh + c0), shb = *(const float4*)(sh + c0 + 4);
    float t0 = fmaxf(fmaf(a0 * di, sca.x, sha.x), 0.f);
    float t1 = fmaxf(fmaf(a1 * di, sca.y, sha.y), 0.f);
    float t2 = fmaxf(fmaf(a2 * di, sca.z, sha.z), 0.f);
    float t3 = fmaxf(fmaf(a3 * di, sca.w, sha.w), 0.f);
    float t4 = fmaxf(fmaf(a4 * di, scb.x, shb.x), 0.f);
    float t5 = fmaxf(fmaf(a5 * di, scb.y, shb.y), 0.f);
    float t6 = fmaxf(fmaf(a6 * di, scb.z, shb.z), 0.f);
    float t7 = fmaxf(fmaf(a7 * di, scb.w, shb.w), 0.f);
    float4 w0 = *(const float4*)(was + 2 * c0);
    float4 w1 = *(const float4*)(was + 2 * c0 + 4);
    float4 w2 = *(const float4*)(was + 2 * c0 + 8);
    float4 w3 = *(const float4*)(was + 2 * c0 + 12);
    float sl0 = t0 * w0.x + t1 * w0.z + t2 * w1.x + t3 * w1.z +
                t4 * w2.x + t5 * w2.z + t6 * w3.x + t7 * w3.z;
    float sl1 = t0 * w0.y + t1 * w0.w + t2 * w1.y + t3 * w1.w +
                t4 * w2.y + t5 * w2.w + t6 * w3.y + t7 * w3.w;
    w0 = *(const float4*)(wad + 2 * c0);
    w1 = *(const float4*)(wad + 2 * c0 + 4);
    w2 = *(const float4*)(wad + 2 * c0 + 8);
    w3 = *(const float4*)(wad + 2 * c0 + 12);
    float dl0 = t0 * w0.x + t1 * w0.z + t2 * w1.x + t3 * w1.z +
                t4 * w2.x + t5 * w2.z + t6 * w3.x + t7 * w3.z;
    float dl1 = t0 * w0.y + t1 * w0.w + t2 * w1.y + t3 * w1.w +
                t4 * w2.y + t5 * w2.w + t6 * w3.y + t7 * w3.w;
#pragma unroll
    for (int mask = 1; mask <= 8; mask <<= 1) {
      sl0 += __shfl_xor(sl0, mask, 64);
      sl1 += __shfl_xor(sl1, mask, 64);
      dl0 += __shfl_xor(dl0, mask, 64);
      dl1 += __shfl_xor(dl1, mask, 64);
    }
    if (l16 == 0) {
      *(float2*)(als + 2 * i) = make_float2(sl0, sl1);
      *(float2*)(ald + 2 * i) = make_float2(dl0, dl1);
    }
    uint4 pw;
    pw.x = (unsigned int)f2b(t0) | ((unsigned int)f2b(t1) << 16);
    pw.y = (unsigned int)f2b(t2) | ((unsigned int)f2b(t3) << 16);
    pw.z = (unsigned int)f2b(t4) | ((unsigned int)f2b(t5) << 16);
    pw.w = (unsigned int)f2b(t6) | ((unsigned int)f2b(t7) << 16);
    *(uint4*)(out + (size_t)i * 128 + l16 * 8) = pw;
  }
}

// -------- GAT-1 aggregation over P (pre-GEMM, 256B rows): one row read per
// -------- edge serves BOTH heads. Q[i] = [r0*agg0 | r1*agg1], r_h=0.5/den_h.
__global__ __launch_bounds__(256) void gat1_pull(const unsigned short* __restrict__ P,
                                                 const int2* __restrict__ aen,
                                                 const int* __restrict__ roff,
                                                 const int* __restrict__ deg,
                                                 const float* __restrict__ als,
                                                 const float* __restrict__ ald,
                                                 unsigned short* __restrict__ Q) {
  int wv = (blockIdx.x * 256 + threadIdx.x) >> 6;
  int lane = threadIdx.x & 63;
  int q4 = lane >> 4, l16 = lane & 15;
  int qb = lane & 48, l7 = lane & 7;
  int i = 4 * wv + q4;
  if (i >= N_NODES) return;
  int off = roff[i], end = off + deg[i];
  float2 dif = *(const float2*)(ald + 2 * i);
  float p0 = 0.f, p1 = 0.f;
  float g0 = 0.f, g1 = 0.f, g2 = 0.f, g3 = 0.f,
        g4 = 0.f, g5 = 0.f, g6 = 0.f, g7 = 0.f;  // head0
  float h0 = 0.f, h1 = 0.f, h2 = 0.f, h3 = 0.f,
        h4 = 0.f, h5 = 0.f, h6 = 0.f, h7 = 0.f;  // head1
  int j = off;
  int nfull = (end - off) >> 3;
  int2 ae = make_int2(i, 0);
  float2 av = make_float2(-1e30f, -1e30f);
  if (l7 < end - j) {
    ae = aen[j + l7];
    av = *(const float2*)(als + 2 * ae.x);
  }
  for (int t = 0; t < nfull; ++t) {
    int ss[8];
#pragma unroll
    for (int k = 0; k < 8; ++k) ss[k] = __shfl(ae.x, qb + k, 64);
    uint4 vv[8];
#pragma unroll
    for (int k = 0; k < 8; ++k)
      vv[k] = *(const uint4*)((const char*)P + (unsigned)ss[k] * 256u + l16 * 16u);
    float q0 = __expf(leaky(av.x + dif.x));
    float q1 = __expf(leaky(av.y + dif.y));
    j += 8;
    if (l7 < end - j) {
      ae = aen[j + l7];
      av = *(const float2*)(als + 2 * ae.x);
    }
#pragma unroll
    for (int k = 0; k < 8; ++k) {
      float b0 = __shfl(q0, qb + k, 64);
      float b1 = __shfl(q1, qb + k, 64);
      p0 += b0; p1 += b1;
      float c0 = blo(vv[k].x), c1 = bhi(vv[k].x);
      float c2 = blo(vv[k].y), c3 = bhi(vv[k].y);
      float c4 = blo(vv[k].z), c5 = bhi(vv[k].z);
      float c6 = blo(vv[k].w), c7 = bhi(vv[k].w);
      g0 = fmaf(b0, c0, g0); h0 = fmaf(b1, c0, h0);
      g1 = fmaf(b0, c1, g1); h1 = fmaf(b1, c1, h1);
      g2 = fmaf(b0, c2, g2); h2 = fmaf(b1, c2, h2);
      g3 = fmaf(b0, c3, g3); h3 = fmaf(b1, c3, h3);
      g4 = fmaf(b0, c4, g4); h4 = fmaf(b1, c4, h4);
      g5 = fmaf(b0, c5, g5); h5 = fmaf(b1, c5, h5);
      g6 = fmaf(b0, c6, g6); h6 = fmaf(b1, c6, h6);
      g7 = fmaf(b0, c7, g7); h7 = fmaf(b1, c7, h7);
    }
  }
  int rem = end - j;
  if (rem) {
    int ss[8];
#pragma unroll
    for (int k = 0; k < 8; ++k) ss[k] = __shfl(ae.x, qb + k, 64);
    uint4 vv[8];
#pragma unroll
    for (int k = 0; k < 8; ++k)
      if (k < rem)
        vv[k] = *(const uint4*)((const char*)P + (unsigned)ss[k] * 256u + l16 * 16u);
    float q0 = __expf(leaky(av.x + dif.x));
    float q1 = __expf(leaky(av.y + dif.y));
#pragma unroll
    for (int k = 0; k < 8; ++k)
      if (k < rem) {
        float b0 = __shfl(q0, qb + k, 64);
        float b1 = __shfl(q1, qb + k, 64);
        p0 += b0; p1 += b1;
        float c0 = blo(vv[k].x), c1 = bhi(vv[k].x);
        float c2 = blo(vv[k].y), c3 = bhi(vv[k].y);
        float c4 = blo(vv[k].z), c5 = bhi(vv[k].z);
        float c6 = blo(vv[k].w), c7 = bhi(vv[k].w);
        g0 = fmaf(b0, c0, g0); h0 = fmaf(b1, c0, h0);
        g1 = fmaf(b0, c1, g1); h1 = fmaf(b1, c1, h1);
        g2 = fmaf(b0, c2, g2); h2 = fmaf(b1, c2, h2);
        g3 = fmaf(b0, c3, g3); h3 = fmaf(b1, c3, h3);
        g4 = fmaf(b0, c4, g4); h4 = fmaf(b1, c4, h4);
        g5 = fmaf(b0, c5, g5); h5 = fmaf(b1, c5, h5);
        g6 = fmaf(b0, c6, g6); h6 = fmaf(b1, c6, h6);
        g7 = fmaf(b0, c7, g7); h7 = fmaf(b1, c7, h7);
      }
  }
  float2 ai = *(const float2*)(als + 2 * i);
  float es0 = __expf(leaky(ai.x + dif.x));
  float es1 = __expf(leaky(ai.y + dif.y));
  float r0 = 0.5f / (p0 + es0);
  float r1 = 0.5f / (p1 + es1);
  uint4 u = *(const uint4*)((const char*)P + (unsigned)i * 256u + l16 * 16u);
  float c0 = blo(u.x), c1 = bhi(u.x), c2 = blo(u.y), c3 = bhi(u.y);
  float c4 = blo(u.z), c5 = bhi(u.z), c6 = blo(u.w), c7 = bhi(u.w);
  g0 = (g0 + es0 * c0) * r0; g1 = (g1 + es0 * c1) * r0;
  g2 = (g2 + es0 * c2) * r0; g3 = (g3 + es0 * c3) * r0;
  g4 = (g4 + es0 * c4) * r0; g5 = (g5 + es0 * c5) * r0;
  g6 = (g6 + es0 * c6) * r0; g7 = (g7 + es0 * c7) * r0;
  h0 = (h0 + es1 * c0) * r1; h1 = (h1 + es1 * c1) * r1;
  h2 = (h2 + es1 * c2) * r1; h3 = (h3 + es1 * c3) * r1;
  h4 = (h4 + es1 * c4) * r1; h5 = (h5 + es1 * c5) * r1;
  h6 = (h6 + es1 * c6) * r1; h7 = (h7 + es1 * c7) * r1;
  uint4 pw;
  pw.x = (unsigned int)f2b(g0) | ((unsigned int)f2b(g1) << 16);
  pw.y = (unsigned int)f2b(g2) | ((unsigned int)f2b(g3) << 16);
  pw.z = (unsigned int)f2b(g4) | ((unsigned int)f2b(g5) << 16);
  pw.w = (unsigned int)f2b(g6) | ((unsigned int)f2b(g7) << 16);
  *(uint4*)(Q + (size_t)i * 256 + l16 * 8) = pw;
  pw.x = (unsigned int)f2b(h0) | ((unsigned int)f2b(h1) << 16);
  pw.y = (unsigned int)f2b(h2) | ((unsigned int)f2b(h3) << 16);
  pw.z = (unsigned int)f2b(h4) | ((unsigned int)f2b(h5) << 16);
  pw.w = (unsigned int)f2b(h6) | ((unsigned int)f2b(h7) << 16);
  *(uint4*)(Q + (size_t)i * 256 + 128 + l16 * 8) = pw;
}

// ---- GAT HD=64 + fused log_softmax: 4 nodes/wave (16 lanes x 16B = 256B row).
__global__ __launch_bounds__(256) void gat_pull64_lsm(const unsigned short* __restrict__ Hb,
                                                      const int2* __restrict__ aen,
                                                      const int* __restrict__ roff,
                                                      const int* __restrict__ deg,
                                                      const float* __restrict__ als,
                                                      const float* __restrict__ ald,
                                                      const float* __restrict__ bias,
                                                      float* __restrict__ out) {
  int wv = (blockIdx.x * 256 + threadIdx.x) >> 6;
  int lane = threadIdx.x & 63;
  int q4 = lane >> 4, l16 = lane & 15;
  int qb = lane & 48, l7 = lane & 7;
  int hh = l16 >> 3, p8 = l16 & 7;
  int i = 4 * wv + q4;
  if (i >= N_NODES) return;
  int off = roff[i], end = off + deg[i];
  unsigned cb2 = (unsigned)(hh * 64 + 8 * p8) * 2u;
  float2 dd = *(const float2*)(ald + 2 * i);
  float p = 0.f;
  float acc0 = 0.f, acc1 = 0.f, acc2 = 0.f, acc3 = 0.f;
  float acc4 = 0.f, acc5 = 0.f, acc6 = 0.f, acc7 = 0.f;
  int j = off;
  int nfull = (end - off) >> 3;
  int2 ae = make_int2(i, 0);
  float2 av = make_float2(-1e30f, -1e30f);
  if (l7 < end - j) {
    ae = aen[j + l7];
    av = *(const float2*)(als + 2 * ae.x);
  }
  for (int t = 0; t < nfull; ++t) {
    int ss[8];
#pragma unroll
    for (int k = 0; k < 8; ++k) ss[k] = __shfl(ae.x, qb + k, 64);
    uint4 vv[8];
#pragma unroll
    for (int k = 0; k < 8; ++k)
      vv[k] = *(const uint4*)((const char*)Hb + (unsigned)ss[k] * 256u + cb2);
    float q0 = __expf(leaky(av.x + dd.x));
    float q1 = __expf(leaky(av.y + dd.y));
    j += 8;
    if (l7 < end - j) {
      ae = aen[j + l7];
      av = *(const float2*)(als + 2 * ae.x);
    }
#pragma unroll
    for (int k = 0; k < 8; ++k) {
      float b0 = __shfl(q0, qb + k, 64);
      float b1 = __shfl(q1, qb + k, 64);
      float q = hh ? b1 : b0;
      p += q;
      acc0 = fmaf(q, blo(vv[k].x), acc0); acc1 = fmaf(q, bhi(vv[k].x), acc1);
      acc2 = fmaf(q, blo(vv[k].y), acc2); acc3 = fmaf(q, bhi(vv[k].y), acc3);
      acc4 = fmaf(q, blo(vv[k].z), acc4); acc5 = fmaf(q, bhi(vv[k].z), acc5);
      acc6 = fmaf(q, blo(vv[k].w), acc6); acc7 = fmaf(q, bhi(vv[k].w), acc7);
    }
  }
  int rem = end - j;
  if (rem) {
    int ss[8];
#pragma unroll
    for (int k = 0; k < 8; ++k) ss[k] = __shfl(ae.x, qb + k, 64);
    uint4 vv[8];
#pragma unroll
    for (int k = 0; k < 8; ++k)
      if (k < rem)
        vv[k] = *(const uint4*)((const char*)Hb + (unsigned)ss[k] * 256u + cb2);
    float q0 = __expf(leaky(av.x + dd.x));
    float q1 = __expf(leaky(av.y + dd.y));
#pragma unroll
    for (int k = 0; k < 8; ++k)
      if (k < rem) {
        float b0 = __shfl(q0, qb + k, 64);
        float b1 = __shfl(q1, qb + k, 64);
        float q = hh ? b1 : b0;
        p += q;
        acc0 = fmaf(q, blo(vv[k].x), acc0); acc1 = fmaf(q, bhi(vv[k].x), acc1);
        acc2 = fmaf(q, blo(vv[k].y), acc2); acc3 = fmaf(q, bhi(vv[k].y), acc3);
        acc4 = fmaf(q, blo(vv[k].z), acc4); acc5 = fmaf(q, bhi(vv[k].z), acc5);
        acc6 = fmaf(q, blo(vv[k].w), acc6); acc7 = fmaf(q, bhi(vv[k].w), acc7);
      }
  }
  float2 ai = *(const float2*)(als + 2 * i);
  float axs = hh ? ai.y : ai.x;
  float dh = hh ? dd.y : dd.x;
  float es = __expf(leaky(axs + dh));
  float rsel = 0.5f / (p + es);
  uint4 u = *(const uint4*)((const char*)Hb + (unsigned)i * 256u + cb2);
  acc0 = (acc0 + es * blo(u.x)) * rsel; acc1 = (acc1 + es * bhi(u.x)) * rsel;
  acc2 = (acc2 + es * blo(u.y)) * rsel; acc3 = (acc3 + es * bhi(u.y)) * rsel;
  acc4 = (acc4 + es * blo(u.z)) * rsel; acc5 = (acc5 + es * bhi(u.z)) * rsel;
  acc6 = (acc6 + es * blo(u.w)) * rsel; acc7 = (acc7 + es * bhi(u.w)) * rsel;
  acc0 += __shfl_xor(acc0, 8, 64); acc1 += __shfl_xor(acc1, 8, 64);
  acc2 += __shfl_xor(acc2, 8, 64); acc3 += __shfl_xor(acc3, 8, 64);
  acc4 += __shfl_xor(acc4, 8, 64); acc5 += __shfl_xor(acc5, 8, 64);
  acc6 += __shfl_xor(acc6, 8, 64); acc7 += __shfl_xor(acc7, 8, 64);
  float4 b0 = *(const float4*)(bias + 8 * p8);
  float4 b1 = *(const float4*)(bias + 8 * p8 + 4);
  float v0 = acc0 + b0.x, v1 = acc1 + b0.y, v2 = acc2 + b0.z, v3 = acc3 + b0.w;
  float v4 = acc4 + b1.x, v5 = acc5 + b1.y, v6 = acc6 + b1.z, v7 = acc7 + b1.w;
  float mv = fmaxf(fmaxf(fmaxf(v0, v1), fmaxf(v2, v3)),
                   fmaxf(fmaxf(v4, v5), fmaxf(v6, v7)));
#pragma unroll
  for (int mm = 4; mm > 0; mm >>= 1) mv = fmaxf(mv, __shfl_xor(mv, mm, 64));
  float sv = __expf(v0 - mv) + __expf(v1 - mv) + __expf(v2 - mv) + __expf(v3 - mv) +
             __expf(v4 - mv) + __expf(v5 - mv) + __expf(v6 - mv) + __expf(v7 - mv);
#pragma unroll
  for (int mm = 4; mm > 0; mm >>= 1) sv += __shfl_xor(sv, mm, 64);
  float ls = mv + __logf(sv);
  if (hh == 0) {
    *(float4*)(out + (size_t)i * 64 + 8 * p8) =
        make_float4(v0 - ls, v1 - ls, v2 - ls, v3 - ls);
    *(float4*)(out + (size_t)i * 64 + 8 * p8 + 4) =
        make_float4(v4 - ls, v5 - ls, v6 - ls, v7 - ls);
  }
}

extern "C" void kernel_launch(void* const* d_in, const int* in_sizes, int n_in, void* d_out,
                              int out_size, void* d_ws, size_t ws_size, hipStream_t stream) {
  const float* x      = (const float*)d_in[0];
  const int* eidx     = (const int*)d_in[1];
  const float* W_gcn1 = (const float*)d_in[2];
  const float* b_gcn1 = (const float*)d_in[3];
  const float* bn1_g  = (const float*)d_in[4];
  const float* bn1_b  = (const float*)d_in[5];
  const float* bn1_m  = (const float*)d_in[6];
  const float* bn1_v  = (const float*)d_in[7];
  const float* W_gat1 = (const float*)d_in[8];
  const float* a_src1 = (const float*)d_in[9];
  const float* a_dst1 = (const float*)d_in[10];
  const float* b_gat1 = (const float*)d_in[11];
  const float* W_gcn2 = (const float*)d_in[12];
  const float* b_gcn2 = (const float*)d_in[13];
  const float* bn2_g  = (const float*)d_in[14];
  const float* bn2_b  = (const float*)d_in[15];
  const float* bn2_m  = (const float*)d_in[16];
  const float* bn2_v  = (const float*)d_in[17];
  const float* W_gat2 = (const float*)d_in[18];
  const float* a_src2 = (const float*)d_in[19];
  const float* a_dst2 = (const float*)d_in[20];
  const float* b_gat2 = (const float*)d_in[21];

  char* ws = (char*)d_ws;
  size_t o = 0;
  auto take = [&](size_t bytes) {
    char* p = ws + o;
    o = (o + bytes + 255) & ~(size_t)255;
    return p;
  };
  int* deg     = (int*)take((size_t)(N_NODES + 64) * 4);  // +1 int (gbase)
  int* gbase   = deg + N_NODES;
  int* roff    = (int*)take((size_t)N_NODES * 4);
  int2* eord   = (int2*)take((size_t)N_EDGES * 8);
  int2* aen    = (int2*)take((size_t)N_EDGES * 8);
  float* dinv  = (float*)take((size_t)N_NODES * 4);
  float* als   = (float*)take((size_t)2 * N_NODES * 4);
  float* ald   = (float*)take((size_t)2 * N_NODES * 4);
  float* sc1   = (float*)take(128 * 4);
  float* sh1   = (float*)take(128 * 4);
  float* sc2   = (float*)take(128 * 4);
  float* sh2   = (float*)take(128 * 4);
  float* was1  = (float*)take(256 * 4);
  float* wad1  = (float*)take(256 * 4);
  float* was2  = (float*)take(256 * 4);
  float* wad2  = (float*)take(256 * 4);
  unsigned short* WtG1 = (unsigned short*)take((size_t)128 * 256 * 2);  // stacked [c][256]
  unsigned short* Wt2  = (unsigned short*)take((size_t)128 * 128 * 2);
  unsigned short* WtG2 = (unsigned short*)take((size_t)128 * 128 * 2);
  unsigned short* Hb   = (unsigned short*)take((size_t)N_NODES * 128 * 2);
  unsigned short* Pb   = (unsigned short*)take((size_t)N_NODES * 128 * 2);
  unsigned short* Qb   = (unsigned short*)take((size_t)N_NODES * 256 * 2);
  unsigned short* Gb   = (unsigned short*)take((size_t)N_NODES * 128 * 2);
  unsigned short* AGb  = (unsigned short*)take((size_t)N_NODES * 128 * 2);
  unsigned short* Q2b  = (unsigned short*)take((size_t)N_NODES * 128 * 2);
  (void)ws_size; (void)in_sizes; (void)n_in; (void)out_size;

  int eb = (N_EDGES + 255) / 256;
  int nb = (N_NODES + 255) / 256;
  int qb = ((N_NODES + 3) / 4 + 3) / 4;    // wave per 4 nodes (pull kernels)
  int gb = (N_NODES + 63) / 64;            // MFMA-GEMM blocks (== GEMM_BLOCKS)

  // CSR build + prep + L1 GEMM, all in one dispatch (block-range split):
  // blocks [0,gb) compute Hb = x@W1 (B-frags from fp32 W1 — no dep on prep),
  // blocks [gb, gb+eb) do edge convert + weight prep.
  hipMemsetAsync(deg, 0, (size_t)(N_NODES + 1) * 4, stream);
  k_convert_gemm<<<gb + eb, 256, 0, stream>>>(
      eidx, deg, eord, x, Hb, W_gcn1, W_gat1, W_gcn2, W_gat2,
      WtG1, Wt2, WtG2, b_gcn1, bn1_g, bn1_b, bn1_m, bn1_v,
      b_gcn2, bn2_g, bn2_b, bn2_m, bn2_v, sc1, sh1, sc2, sh2,
      a_src1, a_dst1, a_src2, a_dst2, was1, wad1, was2, wad2);
  k_offsets<<<nb, 256, 0, stream>>>(deg, gbase, roff, dinv);
  k_fill<<<eb, 256, 0, stream>>>(eord, roff, aen, dinv);

  // Layer pipeline:
  //  L1 GCN : gcn_pull<0> (BN+relu+logits1) over Hb
  //  L2 GAT : gat1_pull (dual-head agg of P) -> gemm_k256 (stacked W, bias, relu)
  //  L3 GCN + L4 GAT proj: gcn_pull<1> (raw agg) -> fused double GEMM (+logits2)
  //  L4 GAT : gat_pull64_lsm
  gcn_pull<0><<<qb, 256, 0, stream>>>(Hb, aen, roff, deg, dinv, sc1, sh1, was1, wad1,
                                      als, ald, Pb);
  gat1_pull<<<qb, 256, 0, stream>>>(Pb, aen, roff, deg, als, ald, Qb);
  gemm_k256<<<gb, 256, 0, stream>>>(Qb, WtG1, b_gat1, Gb);
  gcn_pull<1><<<qb, 256, 0, stream>>>(Gb, aen, roff, deg, dinv, nullptr, nullptr,
                                      nullptr, nullptr, nullptr, nullptr, AGb);
  gemm_gcn2_gat2<<<gb, 256, 0, stream>>>(AGb, Wt2, sc2, sh2, WtG2, was2, wad2,
                                         als, ald, Q2b);
  gat_pull64_lsm<<<qb, 256, 0, stream>>>(Q2b, aen, roff, deg, als, ald, b_gat2,
                                         (float*)d_out);
}